// Round 10
// baseline (1472.891 us; speedup 1.0000x reference)
//
#include <hip/hip_runtime.h>
#include <hip/hip_bf16.h>

#define N_NODES 100000
#define N_EDGES 600000
#define NMP     4
#define NB_SCAN 391   // ceil(N_NODES/256)

typedef __attribute__((ext_vector_type(8))) short bf16x8;
typedef __attribute__((ext_vector_type(4))) float f32x4;

#define LGKM0() asm volatile("s_waitcnt lgkmcnt(0)" ::: "memory")

__device__ __forceinline__ short f2bf(float f) {
    unsigned int u = __float_as_uint(f);
    u += 0x7FFFu + ((u >> 16) & 1u);      // round-to-nearest-even
    return (short)(u >> 16);
}
__device__ __forceinline__ float bf2f(short s) {
    return __uint_as_float(((unsigned int)(unsigned short)s) << 16);
}

// ---------------------------------------------------------------------------
// Pack weights [K][128] f32 -> MFMA B-fragment order bf16:
// frag(kt,nt,lane)[j] = W[kt*32 + (lane>>4)*8 + j][nt*16 + (lane&15)]
// Per-iter packed layout (elems): edge_w0 @0 (49152), edge_w1 @49152 (16384),
// node_w0 @65536 (32768), node_w1 @98304 (16384); iter stride 114688.
// W0c (ea part, kt 8..11) = elems [32768,49152); W1 = [49152,65536).
// ---------------------------------------------------------------------------
__global__ void pack_weights(const float* __restrict__ ew0, const float* __restrict__ ew1,
                             const float* __restrict__ nw0, const float* __restrict__ nw1,
                             short* __restrict__ out) {
    int t = blockIdx.x * blockDim.x + threadIdx.x;
    if (t >= NMP * 14336) return;
    int it = t / 14336;
    int r  = t % 14336;
    const float* W; int obase;
    if (r < 6144)       { W = ew0 + (size_t)it*384*128; obase = 0;     }
    else if (r < 8192)  { W = ew1 + (size_t)it*128*128; obase = 49152; r -= 6144;  }
    else if (r < 12288) { W = nw0 + (size_t)it*256*128; obase = 65536; r -= 8192;  }
    else                { W = nw1 + (size_t)it*128*128; obase = 98304; r -= 12288; }
    int kt   = r >> 9;
    int rem  = r & 511;
    int nt   = rem >> 6;
    int lane = rem & 63;
    short* o = out + (size_t)it*114688 + obase + ((size_t)(kt*8 + nt)*64 + lane)*8;
    int kbase = kt*32 + (lane >> 4)*8;
    int n     = nt*16 + (lane & 15);
    #pragma unroll
    for (int j = 0; j < 8; j++) o[j] = f2bf(W[(size_t)(kbase + j)*128 + n]);
}

// ------------------------- CSR build (once per launch) ----------------------
__global__ void deg_count(const int* __restrict__ tgt, int* __restrict__ deg) {
    int e = blockIdx.x * blockDim.x + threadIdx.x;
    if (e < N_EDGES) atomicAdd(&deg[tgt[e]], 1);
}

__global__ void scan_reduce(const int* __restrict__ deg, int* __restrict__ bsum) {
    __shared__ int sh[256];
    int i = blockIdx.x * 256 + threadIdx.x;
    sh[threadIdx.x] = (i < N_NODES) ? deg[i] : 0;
    __syncthreads();
    for (int d = 128; d > 0; d >>= 1) {
        if (threadIdx.x < d) sh[threadIdx.x] += sh[threadIdx.x + d];
        __syncthreads();
    }
    if (threadIdx.x == 0) bsum[blockIdx.x] = sh[0];
}

__global__ void scan_top(const int* __restrict__ bsum, int* __restrict__ bbase,
                         int* __restrict__ off) {
    if (threadIdx.x == 0 && blockIdx.x == 0) {
        int run = 0;
        for (int b = 0; b < NB_SCAN; b++) { bbase[b] = run; run += bsum[b]; }
        off[N_NODES] = run;
    }
}

__global__ void scan_apply(const int* __restrict__ deg, const int* __restrict__ bbase,
                           int* __restrict__ off, int* __restrict__ cursor) {
    __shared__ int sh[256];
    int i = blockIdx.x * 256 + threadIdx.x;
    int v = (i < N_NODES) ? deg[i] : 0;
    sh[threadIdx.x] = v;
    __syncthreads();
    int acc = v;
    for (int d = 1; d < 256; d <<= 1) {
        int t = (threadIdx.x >= d) ? sh[threadIdx.x - d] : 0;
        __syncthreads();
        acc += t;
        sh[threadIdx.x] = acc;
        __syncthreads();
    }
    if (i < N_NODES) {
        int o = bbase[blockIdx.x] + acc - v;   // exclusive
        off[i] = o;
        cursor[i] = o;
    }
}

__global__ void fill_csr(const int* __restrict__ tgt, int* __restrict__ cursor,
                         int* __restrict__ elist) {
    int e = blockIdx.x * blockDim.x + threadIdx.x;
    if (e < N_EDGES) {
        int p = atomicAdd(&cursor[tgt[e]], 1);
        elist[p] = e;
    }
}

// psrc/ptgt: src/tgt per SORTED edge position
__global__ void build_perm(const int* __restrict__ srcI, const int* __restrict__ tgtI,
                           const int* __restrict__ elist,
                           int* __restrict__ psrc, int* __restrict__ ptgt) {
    int k = blockIdx.x * blockDim.x + threadIdx.x;
    if (k < N_EDGES) {
        int e = elist[k];
        psrc[k] = srcI[e];
        ptgt[k] = tgtI[e];
    }
}

// ---------------------------------------------------------------------------
// xform: P = x@W0a, Q = x@W0b  (bf16 outputs, [N][128] each) — iter 0 only.
// ---------------------------------------------------------------------------
__global__ __launch_bounds__(256)
void xform_kernel(const float* __restrict__ x_in,
                  short* __restrict__ P, short* __restrict__ Q,
                  const short* __restrict__ w0p) {
    const int tid  = threadIdx.x;
    const int wave = tid >> 6, lane = tid & 63;
    const int l15  = lane & 15, lg = lane >> 4;
    const long long nbase = (long long)blockIdx.x * 64 + wave * 16;
    long long arow = nbase + l15;
    if (arow >= N_NODES) arow = N_NODES - 1;

    f32x4 accP[8] = {}, accQ[8] = {};
    const bf16x8* w0f = (const bf16x8*)w0p;
    #pragma unroll
    for (int kt = 0; kt < 4; kt++) {
        const float* ap = x_in + arow*128 + kt*32 + lg*8;
        float4 f0 = *(const float4*)ap;
        float4 f1 = *(const float4*)(ap + 4);
        bf16x8 af;
        af[0]=f2bf(f0.x); af[1]=f2bf(f0.y); af[2]=f2bf(f0.z); af[3]=f2bf(f0.w);
        af[4]=f2bf(f1.x); af[5]=f2bf(f1.y); af[6]=f2bf(f1.z); af[7]=f2bf(f1.w);
        #pragma unroll
        for (int nt = 0; nt < 8; nt++) {
            accP[nt] = __builtin_amdgcn_mfma_f32_16x16x32_bf16(af, w0f[(size_t)(kt*8 + nt)*64 + lane], accP[nt], 0, 0, 0);
            accQ[nt] = __builtin_amdgcn_mfma_f32_16x16x32_bf16(af, w0f[(size_t)((kt+4)*8 + nt)*64 + lane], accQ[nt], 0, 0, 0);
        }
    }
    #pragma unroll
    for (int nt = 0; nt < 8; nt++) {
        int col = nt*16 + l15;
        #pragma unroll
        for (int j = 0; j < 4; j++) {
            long long r = nbase + lg*4 + j;
            if (r < N_NODES) {
                P[r*128 + col] = f2bf(accP[nt][j]);
                Q[r*128 + col] = f2bf(accQ[nt][j]);
            }
        }
    }
}

// ---------------------------------------------------------------------------
// Edge kernel (CSR-sorted): 512 threads (8 waves), 128 edges/block.
// ZERO barriers, LDS = per-wave pq tiles only (35.8KB -> 4 blocks/CU,
// 32-wave occupancy cap). ALL weight B-frags (W0c||W1, 64KB shared by every
// block) read straight from global -> L2-resident. Wide dwordx4 epilogue
// stores via LDS staging (r9).
// ---------------------------------------------------------------------------
template<bool EAF32>
__global__ __launch_bounds__(512)
void edge_kernel(const short* __restrict__ P,
                 const short* __restrict__ Q,
                 const void* __restrict__ ea_in_v,
                 short* __restrict__ ea_out,
                 const int* __restrict__ psrc,
                 const int* __restrict__ ptgt,
                 const int* __restrict__ elist,
                 const short* __restrict__ w0p,
                 const float* __restrict__ b0,
                 const float* __restrict__ b1,
                 const float* __restrict__ lng,
                 const float* __restrict__ lnb) {
    __shared__ __align__(16) short pq[8][16][140];   // 35840B per-wave tiles
    const int tid  = threadIdx.x;
    const int wave = tid >> 6, lane = tid & 63;
    const int l15  = lane & 15, lg = lane >> 4;
    const long long ebase = (long long)blockIdx.x * 128 + wave * 16;
    const long long arow  = ebase + l15;
    const long long arc   = arow < N_EDGES ? arow : (N_EDGES - 1);
    const float* eaf = (const float*)ea_in_v;
    const short* eab = (const short*)ea_in_v;
    const bf16x8* w0c = (const bf16x8*)(w0p + 32768);   // W0c frags (L2)
    const bf16x8* w1f = (const bf16x8*)(w0p + 49152);   // W1  frags (L2)

    // --- per-wave gather: P[psrc]+Q[ptgt] summed in registers ---
    {
        const int c8 = (lane & 7) * 16;        // 32B column chunk (shorts)
        #pragma unroll
        for (int pass = 0; pass < 2; pass++) {
            int rr = (lane >> 3) + pass * 8;
            long long e = ebase + rr;
            if (e >= N_EDGES) e = N_EDGES - 1;
            long long s = psrc[e], t = ptgt[e];
            bf16x8 p0 = *(const bf16x8*)(P + s*128 + c8);
            bf16x8 p1 = *(const bf16x8*)(P + s*128 + c8 + 8);
            bf16x8 q0 = *(const bf16x8*)(Q + t*128 + c8);
            bf16x8 q1 = *(const bf16x8*)(Q + t*128 + c8 + 8);
            bf16x8 u0, u1;
            #pragma unroll
            for (int k = 0; k < 8; k++) {
                u0[k] = f2bf(bf2f(p0[k]) + bf2f(q0[k]));
                u1[k] = f2bf(bf2f(p1[k]) + bf2f(q1[k]));
            }
            *(bf16x8*)&pq[wave][rr][c8]     = u0;
            *(bf16x8*)&pq[wave][rr][c8 + 8] = u1;
        }
    }

    // --- load ea fragments (A-operand + residual) ---
    bf16x8 eafrag[4];
    #pragma unroll
    for (int kt = 0; kt < 4; kt++) {
        if (EAF32) {
            long long orig = elist[arc];          // one-time scatter at iter 0
            const float* ap = eaf + orig*128 + kt*32 + lg*8;
            float4 f0 = *(const float4*)ap;
            float4 f1 = *(const float4*)(ap + 4);
            bf16x8 af;
            af[0]=f2bf(f0.x); af[1]=f2bf(f0.y); af[2]=f2bf(f0.z); af[3]=f2bf(f0.w);
            af[4]=f2bf(f1.x); af[5]=f2bf(f1.y); af[6]=f2bf(f1.z); af[7]=f2bf(f1.w);
            eafrag[kt] = af;
        } else {
            eafrag[kt] = *(const bf16x8*)(eab + arc*128 + kt*32 + lg*8);
        }
    }

    // --- layer0: ea @ W0c (B-frags from global/L2) ---
    f32x4 acc[8] = {};
    #pragma unroll
    for (int kt = 0; kt < 4; kt++) {
        #pragma unroll
        for (int nt = 0; nt < 8; nt++) {
            bf16x8 bfr = w0c[(size_t)(kt*8 + nt)*64 + lane];
            acc[nt] = __builtin_amdgcn_mfma_f32_16x16x32_bf16(eafrag[kt], bfr, acc[nt], 0, 0, 0);
        }
    }

    // --- bias + PQ add + ELU; hidden in place (lane-owned) ---
    #pragma unroll
    for (int nt = 0; nt < 8; nt++) {
        int col = nt*16 + l15;
        float bb = b0[col];
        #pragma unroll
        for (int j = 0; j < 4; j++) {
            int r = lg*4 + j;
            float v = acc[nt][j] + bb + bf2f(pq[wave][r][col]);
            v = v > 0.f ? v : (__expf(v) - 1.f);
            pq[wave][r][col] = f2bf(v);
        }
    }
    LGKM0();   // hidden visible to all lanes of this wave

    // --- layer1: hid @ W1 (B-frags from global/L2) ---
    f32x4 acc2[8] = {};
    #pragma unroll
    for (int kt = 0; kt < 4; kt++) {
        bf16x8 af = *(const bf16x8*)&pq[wave][l15][kt*32 + lg*8];
        #pragma unroll
        for (int nt = 0; nt < 8; nt++) {
            bf16x8 bfr = w1f[(size_t)(kt*8 + nt)*64 + lane];
            acc2[nt] = __builtin_amdgcn_mfma_f32_16x16x32_bf16(af, bfr, acc2[nt], 0, 0, 0);
        }
    }
    LGKM0();   // hidden ds_reads drained -> tile reusable

    // --- stage ea fragments (residual source) ---
    #pragma unroll
    for (int kt = 0; kt < 4; kt++)
        *(bf16x8*)&pq[wave][l15][kt*32 + lg*8] = eafrag[kt];
    LGKM0();

    // --- residual (LDS) + LayerNorm ---
    float t[8][4];
    #pragma unroll
    for (int nt = 0; nt < 8; nt++) {
        int col = nt*16 + l15;
        float bb = b1[col];
        #pragma unroll
        for (int j = 0; j < 4; j++) {
            int r = lg*4 + j;
            t[nt][j] = acc2[nt][j] + bb + bf2f(pq[wave][r][col]);
        }
    }
    LGKM0();   // all residual reads done -> tile reusable for output staging

    #pragma unroll
    for (int j = 0; j < 4; j++) {
        float s = 0.f;
        #pragma unroll
        for (int nt = 0; nt < 8; nt++) s += t[nt][j];
        #pragma unroll
        for (int m = 1; m < 16; m <<= 1) s += __shfl_xor(s, m);
        float mean = s * (1.0f / 128.0f);
        float s2 = 0.f;
        #pragma unroll
        for (int nt = 0; nt < 8; nt++) { float d = t[nt][j] - mean; s2 += d*d; }
        #pragma unroll
        for (int m = 1; m < 16; m <<= 1) s2 += __shfl_xor(s2, m);
        float rstd = rsqrtf(s2 * (1.0f / 128.0f) + 1e-5f);
        int r = lg*4 + j;
        #pragma unroll
        for (int nt = 0; nt < 8; nt++) {
            int col = nt*16 + l15;
            pq[wave][r][col] = f2bf((t[nt][j] - mean) * rstd * lng[col] + lnb[col]);
        }
    }
    LGKM0();   // LN output staged (wave-local)

    // --- wide coalesced store: wave streams its 16 rows (4KB) ---
    #pragma unroll
    for (int k = 0; k < 4; k++) {
        int row = k*4 + (lane >> 4);
        long long erow = ebase + row;
        bf16x8 vv = *(const bf16x8*)&pq[wave][row][l15*8];
        if (erow < N_EDGES)
            *(bf16x8*)&ea_out[erow*128 + l15*8] = vv;
    }
}

// ---------------------------------------------------------------------------
// Aggregation: one wave per node; ea rows for node n are CONTIGUOUS
// [off[n], off[n+1]) in the permuted layout -> pure streaming read.
// ---------------------------------------------------------------------------
__global__ __launch_bounds__(256)
void agg_kernel(const short* __restrict__ ea,
                const int* __restrict__ off,
                short* __restrict__ aggb) {
    const int wid  = (blockIdx.x * 256 + threadIdx.x) >> 6;
    const int lane = threadIdx.x & 63;
    if (wid >= N_NODES) return;
    const int o0 = off[wid], o1 = off[wid + 1];
    float s0 = 0.f, s1 = 0.f;
    for (int i = o0; i < o1; i++) {
        unsigned int v = *(const unsigned int*)(ea + (long long)i*128 + lane*2);
        s0 += __uint_as_float(v << 16);
        s1 += __uint_as_float(v & 0xFFFF0000u);
    }
    float inv = (o1 > o0) ? 1.f / (float)(o1 - o0) : 0.f;
    short2 w;
    w.x = f2bf(s0 * inv);
    w.y = f2bf(s1 * inv);
    *(short2*)(aggb + (long long)wid*128 + lane*2) = w;
}

// ---------------------------------------------------------------------------
// Node kernel + fused P/Q production for the NEXT iteration.
// ---------------------------------------------------------------------------
template<bool MAKEPQ>
__global__ __launch_bounds__(256)
void node_kernel(const float* __restrict__ x_in,
                 float* __restrict__ x_out,
                 const short* __restrict__ aggb,
                 const short* __restrict__ w0p,
                 const short* __restrict__ w1p,
                 const short* __restrict__ wnext,   // next iter edge W0a/b frags
                 short* __restrict__ P,
                 short* __restrict__ Q,
                 const float* __restrict__ b0,
                 const float* __restrict__ b1,
                 const float* __restrict__ lng,
                 const float* __restrict__ lnb) {
    __shared__ __align__(16) short hid[4][16][140];
    const int tid  = threadIdx.x;
    const int wave = tid >> 6, lane = tid & 63;
    const int l15  = lane & 15, lg = lane >> 4;
    const long long nbase = (long long)blockIdx.x * 64 + wave * 16;
    long long arow = nbase + l15;
    if (arow >= N_NODES) arow = N_NODES - 1;

    f32x4 acc[8] = {};
    const bf16x8* w0f = (const bf16x8*)w0p;
    #pragma unroll
    for (int kt = 0; kt < 8; kt++) {
        int k0 = kt*32 + lg*8;
        bf16x8 af;
        if (k0 < 128) {
            const float* ap = x_in + arow*128 + k0;
            float4 f0 = *(const float4*)ap;
            float4 f1 = *(const float4*)(ap + 4);
            af[0]=f2bf(f0.x); af[1]=f2bf(f0.y); af[2]=f2bf(f0.z); af[3]=f2bf(f0.w);
            af[4]=f2bf(f1.x); af[5]=f2bf(f1.y); af[6]=f2bf(f1.z); af[7]=f2bf(f1.w);
        } else {
            af = *(const bf16x8*)(aggb + arow*128 + (k0 - 128));
        }
        #pragma unroll
        for (int nt = 0; nt < 8; nt++) {
            bf16x8 bfr = w0f[(size_t)(kt*8 + nt)*64 + lane];
            acc[nt] = __builtin_amdgcn_mfma_f32_16x16x32_bf16(af, bfr, acc[nt], 0, 0, 0);
        }
    }
    #pragma unroll
    for (int nt = 0; nt < 8; nt++) {
        int col = nt*16 + l15;
        float bb = b0[col];
        #pragma unroll
        for (int j = 0; j < 4; j++) {
            float v = acc[nt][j] + bb;
            v = v > 0.f ? v : (__expf(v) - 1.f);
            hid[wave][lg*4 + j][col] = f2bf(v);
        }
    }
    LGKM0();   // hid writes complete (wave-local)

    f32x4 acc2[8] = {};
    const bf16x8* w1f = (const bf16x8*)w1p;
    #pragma unroll
    for (int kt = 0; kt < 4; kt++) {
        bf16x8 af = *(const bf16x8*)&hid[wave][l15][kt*32 + lg*8];
        #pragma unroll
        for (int nt = 0; nt < 8; nt++) {
            bf16x8 bfr = w1f[(size_t)(kt*8 + nt)*64 + lane];
            acc2[nt] = __builtin_amdgcn_mfma_f32_16x16x32_bf16(af, bfr, acc2[nt], 0, 0, 0);
        }
    }
    float t[8][4];
    #pragma unroll
    for (int nt = 0; nt < 8; nt++) {
        int col = nt*16 + l15;
        float bb = b1[col];
        #pragma unroll
        for (int j = 0; j < 4; j++) {
            long long nrow = nbase + lg*4 + j;
            long long nrc  = nrow < N_NODES ? nrow : (N_NODES - 1);
            t[nt][j] = acc2[nt][j] + bb + x_in[nrc*128 + col];
        }
    }
    float xo[8][4];
    #pragma unroll
    for (int j = 0; j < 4; j++) {
        float s = 0.f;
        #pragma unroll
        for (int nt = 0; nt < 8; nt++) s += t[nt][j];
        #pragma unroll
        for (int m = 1; m < 16; m <<= 1) s += __shfl_xor(s, m);
        float mean = s * (1.0f / 128.0f);
        float s2 = 0.f;
        #pragma unroll
        for (int nt = 0; nt < 8; nt++) { float d = t[nt][j] - mean; s2 += d*d; }
        #pragma unroll
        for (int m = 1; m < 16; m <<= 1) s2 += __shfl_xor(s2, m);
        float rstd = rsqrtf(s2 * (1.0f / 128.0f) + 1e-5f);
        long long nrow = nbase + lg*4 + j;
        #pragma unroll
        for (int nt = 0; nt < 8; nt++) {
            int col = nt*16 + l15;
            float v = (t[nt][j] - mean) * rstd * lng[col] + lnb[col];
            xo[nt][j] = v;
            if (nrow < N_NODES) x_out[nrow*128 + col] = v;
        }
    }

    if (MAKEPQ) {
        LGKM0();   // layer1 ds_reads drained
        #pragma unroll
        for (int nt = 0; nt < 8; nt++) {
            int col = nt*16 + l15;
            #pragma unroll
            for (int j = 0; j < 4; j++)
                hid[wave][lg*4 + j][col] = f2bf(xo[nt][j]);
        }
        LGKM0();

        const bf16x8* wn = (const bf16x8*)wnext;
        {
            f32x4 accP[8] = {};
            #pragma unroll
            for (int kt = 0; kt < 4; kt++) {
                bf16x8 af = *(const bf16x8*)&hid[wave][l15][kt*32 + lg*8];
                #pragma unroll
                for (int nt = 0; nt < 8; nt++)
                    accP[nt] = __builtin_amdgcn_mfma_f32_16x16x32_bf16(af, wn[(size_t)(kt*8 + nt)*64 + lane], accP[nt], 0, 0, 0);
            }
            #pragma unroll
            for (int nt = 0; nt < 8; nt++) {
                int col = nt*16 + l15;
                #pragma unroll
                for (int j = 0; j < 4; j++) {
                    long long r = nbase + lg*4 + j;
                    if (r < N_NODES) P[r*128 + col] = f2bf(accP[nt][j]);
                }
            }
        }
        {
            f32x4 accQ[8] = {};
            #pragma unroll
            for (int kt = 0; kt < 4; kt++) {
                bf16x8 af = *(const bf16x8*)&hid[wave][l15][kt*32 + lg*8];
                #pragma unroll
                for (int nt = 0; nt < 8; nt++)
                    accQ[nt] = __builtin_amdgcn_mfma_f32_16x16x32_bf16(af, wn[(size_t)((kt+4)*8 + nt)*64 + lane], accQ[nt], 0, 0, 0);
            }
            #pragma unroll
            for (int nt = 0; nt < 8; nt++) {
                int col = nt*16 + l15;
                #pragma unroll
                for (int j = 0; j < 4; j++) {
                    long long r = nbase + lg*4 + j;
                    if (r < N_NODES) Q[r*128 + col] = f2bf(accQ[nt][j]);
                }
            }
        }
    }
}

extern "C" void kernel_launch(void* const* d_in, const int* in_sizes, int n_in,
                              void* d_out, int out_size, void* d_ws, size_t ws_size,
                              hipStream_t stream) {
    const float* x_in   = (const float*)d_in[0];
    const int*   eidx   = (const int*)d_in[1];
    const float* ea_in0 = (const float*)d_in[2];
    const float* ew0  = (const float*)d_in[5];
    const float* eb0  = (const float*)d_in[6];
    const float* ew1  = (const float*)d_in[7];
    const float* eb1  = (const float*)d_in[8];
    const float* elng = (const float*)d_in[9];
    const float* elnb = (const float*)d_in[10];
    const float* nw0  = (const float*)d_in[11];
    const float* nb0  = (const float*)d_in[12];
    const float* nw1  = (const float*)d_in[13];
    const float* nb1  = (const float*)d_in[14];
    const float* nlng = (const float*)d_in[15];
    const float* nlnb = (const float*)d_in[16];
    const int* srcI = eidx;
    const int* tgtI = eidx + N_EDGES;

    // ---- workspace layout (bytes) ----
    char* ws = (char*)d_ws;
    size_t o = 0;
    short* ea_bf  = (short*)(ws + o); o += (size_t)N_EDGES * 128 * 2;       // 153.6 MB (permuted)
    short* Pb     = (short*)(ws + o); o += (size_t)N_NODES * 128 * 2;       // 25.6 MB
    short* Qb     = (short*)(ws + o); o += (size_t)N_NODES * 128 * 2;       // 25.6 MB
    short* aggb   = (short*)(ws + o); o += (size_t)N_NODES * 128 * 2;       // 25.6 MB
    short* wpack  = (short*)(ws + o); o += (size_t)NMP * 114688 * 2;        // 0.92 MB
    int*   deg    = (int*)(ws + o);   o += (size_t)N_NODES * 4;
    int*   offA   = (int*)(ws + o);   o += (size_t)(N_NODES + 1) * 4;
    int*   cursor = (int*)(ws + o);   o += (size_t)N_NODES * 4;
    int*   bsum   = (int*)(ws + o);   o += (size_t)NB_SCAN * 4;
    int*   bbase  = (int*)(ws + o);   o += (size_t)NB_SCAN * 4;
    int*   elist  = (int*)(ws + o);   o += (size_t)N_EDGES * 4;
    int*   psrc   = (int*)(ws + o);   o += (size_t)N_EDGES * 4;
    int*   ptgt   = (int*)(ws + o);   o += (size_t)N_EDGES * 4;
    float* xbuf   = (float*)d_out;

    // ---- one-time: weight pack + CSR + permuted index arrays ----
    pack_weights<<<(NMP * 14336 + 255) / 256, 256, 0, stream>>>(ew0, ew1, nw0, nw1, wpack);
    hipMemsetAsync(deg, 0, (size_t)N_NODES * 4, stream);
    deg_count<<<(N_EDGES + 255) / 256, 256, 0, stream>>>(tgtI, deg);
    scan_reduce<<<NB_SCAN, 256, 0, stream>>>(deg, bsum);
    scan_top<<<1, 64, 0, stream>>>(bsum, bbase, offA);
    scan_apply<<<NB_SCAN, 256, 0, stream>>>(deg, bbase, offA, cursor);
    fill_csr<<<(N_EDGES + 255) / 256, 256, 0, stream>>>(tgtI, cursor, elist);
    build_perm<<<(N_EDGES + 255) / 256, 256, 0, stream>>>(srcI, tgtI, elist, psrc, ptgt);

    const int ngrid = (N_NODES + 63) / 64;
    const int egrid = (N_EDGES + 127) / 128;
    // iter-0 P/Q from input x
    xform_kernel<<<ngrid, 256, 0, stream>>>(x_in, Pb, Qb, wpack);

    for (int i = 0; i < NMP; i++) {
        const float* xg = (i == 0) ? x_in : xbuf;
        const short* wp = wpack + (size_t)i * 114688;
        const short* wnext = wpack + (size_t)(i + 1) * 114688;   // unused when i==3
        if (i == 0) {
            edge_kernel<true><<<egrid, 512, 0, stream>>>(
                Pb, Qb, (const void*)ea_in0, ea_bf, psrc, ptgt, elist,
                wp + 0,
                eb0 + i * 128, eb1 + i * 128, elng + i * 128, elnb + i * 128);
        } else {
            edge_kernel<false><<<egrid, 512, 0, stream>>>(
                Pb, Qb, (const void*)ea_bf, ea_bf, psrc, ptgt, elist,
                wp + 0,
                eb0 + i * 128, eb1 + i * 128, elng + i * 128, elnb + i * 128);
        }
        agg_kernel<<<(N_NODES * 64 + 255) / 256, 256, 0, stream>>>(ea_bf, offA, aggb);
        if (i < NMP - 1) {
            node_kernel<true><<<ngrid, 256, 0, stream>>>(
                xg, xbuf, aggb,
                wp + 65536, wp + 98304, wnext, Pb, Qb,
                nb0 + i * 128, nb1 + i * 128, nlng + i * 128, nlnb + i * 128);
        } else {
            node_kernel<false><<<ngrid, 256, 0, stream>>>(
                xg, xbuf, aggb,
                wp + 65536, wp + 98304, wnext, Pb, Qb,
                nb0 + i * 128, nb1 + i * 128, nlng + i * 128, nlnb + i * 128);
        }
    }
}

// Round 13
// 1285.181 us; speedup vs baseline: 1.1461x; 1.1461x over previous
//
#include <hip/hip_runtime.h>
#include <hip/hip_bf16.h>

#define N_NODES 100000
#define N_EDGES 600000
#define NMP     4
#define NB_SCAN 391   // ceil(N_NODES/256)

typedef __attribute__((ext_vector_type(8))) short bf16x8;
typedef __attribute__((ext_vector_type(4))) float f32x4;

#define LGKM0() asm volatile("s_waitcnt lgkmcnt(0)" ::: "memory")

__device__ __forceinline__ short f2bf(float f) {
    unsigned int u = __float_as_uint(f);
    u += 0x7FFFu + ((u >> 16) & 1u);      // round-to-nearest-even
    return (short)(u >> 16);
}
__device__ __forceinline__ float bf2f(short s) {
    return __uint_as_float(((unsigned int)(unsigned short)s) << 16);
}

// ---------------------------------------------------------------------------
// Pack weights [K][128] f32 -> MFMA B-fragment order bf16:
// frag(kt,nt,lane)[j] = W[kt*32 + (lane>>4)*8 + j][nt*16 + (lane&15)]
// Per-iter packed layout (elems): edge_w0 @0 (49152), edge_w1 @49152 (16384),
// node_w0 @65536 (32768), node_w1 @98304 (16384); iter stride 114688.
// W0c (ea part, kt 8..11) = elems [32768,49152); W1 = [49152,65536).
// ---------------------------------------------------------------------------
__global__ void pack_weights(const float* __restrict__ ew0, const float* __restrict__ ew1,
                             const float* __restrict__ nw0, const float* __restrict__ nw1,
                             short* __restrict__ out) {
    int t = blockIdx.x * blockDim.x + threadIdx.x;
    if (t >= NMP * 14336) return;
    int it = t / 14336;
    int r  = t % 14336;
    const float* W; int obase;
    if (r < 6144)       { W = ew0 + (size_t)it*384*128; obase = 0;     }
    else if (r < 8192)  { W = ew1 + (size_t)it*128*128; obase = 49152; r -= 6144;  }
    else if (r < 12288) { W = nw0 + (size_t)it*256*128; obase = 65536; r -= 8192;  }
    else                { W = nw1 + (size_t)it*128*128; obase = 98304; r -= 12288; }
    int kt   = r >> 9;
    int rem  = r & 511;
    int nt   = rem >> 6;
    int lane = rem & 63;
    short* o = out + (size_t)it*114688 + obase + ((size_t)(kt*8 + nt)*64 + lane)*8;
    int kbase = kt*32 + (lane >> 4)*8;
    int n     = nt*16 + (lane & 15);
    #pragma unroll
    for (int j = 0; j < 8; j++) o[j] = f2bf(W[(size_t)(kbase + j)*128 + n]);
}

// ------------------------- CSR build (once per launch) ----------------------
__global__ void deg_count(const int* __restrict__ tgt, int* __restrict__ deg) {
    int e = blockIdx.x * blockDim.x + threadIdx.x;
    if (e < N_EDGES) atomicAdd(&deg[tgt[e]], 1);
}

__global__ void scan_reduce(const int* __restrict__ deg, int* __restrict__ bsum) {
    __shared__ int sh[256];
    int i = blockIdx.x * 256 + threadIdx.x;
    sh[threadIdx.x] = (i < N_NODES) ? deg[i] : 0;
    __syncthreads();
    for (int d = 128; d > 0; d >>= 1) {
        if (threadIdx.x < d) sh[threadIdx.x] += sh[threadIdx.x + d];
        __syncthreads();
    }
    if (threadIdx.x == 0) bsum[blockIdx.x] = sh[0];
}

__global__ void scan_top(const int* __restrict__ bsum, int* __restrict__ bbase,
                         int* __restrict__ off) {
    if (threadIdx.x == 0 && blockIdx.x == 0) {
        int run = 0;
        for (int b = 0; b < NB_SCAN; b++) { bbase[b] = run; run += bsum[b]; }
        off[N_NODES] = run;
    }
}

__global__ void scan_apply(const int* __restrict__ deg, const int* __restrict__ bbase,
                           int* __restrict__ off, int* __restrict__ cursor) {
    __shared__ int sh[256];
    int i = blockIdx.x * 256 + threadIdx.x;
    int v = (i < N_NODES) ? deg[i] : 0;
    sh[threadIdx.x] = v;
    __syncthreads();
    int acc = v;
    for (int d = 1; d < 256; d <<= 1) {
        int t = (threadIdx.x >= d) ? sh[threadIdx.x - d] : 0;
        __syncthreads();
        acc += t;
        sh[threadIdx.x] = acc;
        __syncthreads();
    }
    if (i < N_NODES) {
        int o = bbase[blockIdx.x] + acc - v;   // exclusive
        off[i] = o;
        cursor[i] = o;
    }
}

__global__ void fill_csr(const int* __restrict__ tgt, int* __restrict__ cursor,
                         int* __restrict__ elist) {
    int e = blockIdx.x * blockDim.x + threadIdx.x;
    if (e < N_EDGES) {
        int p = atomicAdd(&cursor[tgt[e]], 1);
        elist[p] = e;
    }
}

// psrc/ptgt: src/tgt per SORTED edge position
__global__ void build_perm(const int* __restrict__ srcI, const int* __restrict__ tgtI,
                           const int* __restrict__ elist,
                           int* __restrict__ psrc, int* __restrict__ ptgt) {
    int k = blockIdx.x * blockDim.x + threadIdx.x;
    if (k < N_EDGES) {
        int e = elist[k];
        psrc[k] = srcI[e];
        ptgt[k] = tgtI[e];
    }
}

// ---------------------------------------------------------------------------
// xform: P = x@W0a, Q = x@W0b  (bf16 outputs, [N][128] each) — iter 0 only.
// ---------------------------------------------------------------------------
__global__ __launch_bounds__(256)
void xform_kernel(const float* __restrict__ x_in,
                  short* __restrict__ P, short* __restrict__ Q,
                  const short* __restrict__ w0p) {
    const int tid  = threadIdx.x;
    const int wave = tid >> 6, lane = tid & 63;
    const int l15  = lane & 15, lg = lane >> 4;
    const long long nbase = (long long)blockIdx.x * 64 + wave * 16;
    long long arow = nbase + l15;
    if (arow >= N_NODES) arow = N_NODES - 1;

    f32x4 accP[8] = {}, accQ[8] = {};
    const bf16x8* w0f = (const bf16x8*)w0p;
    #pragma unroll
    for (int kt = 0; kt < 4; kt++) {
        const float* ap = x_in + arow*128 + kt*32 + lg*8;
        float4 f0 = *(const float4*)ap;
        float4 f1 = *(const float4*)(ap + 4);
        bf16x8 af;
        af[0]=f2bf(f0.x); af[1]=f2bf(f0.y); af[2]=f2bf(f0.z); af[3]=f2bf(f0.w);
        af[4]=f2bf(f1.x); af[5]=f2bf(f1.y); af[6]=f2bf(f1.z); af[7]=f2bf(f1.w);
        #pragma unroll
        for (int nt = 0; nt < 8; nt++) {
            accP[nt] = __builtin_amdgcn_mfma_f32_16x16x32_bf16(af, w0f[(size_t)(kt*8 + nt)*64 + lane], accP[nt], 0, 0, 0);
            accQ[nt] = __builtin_amdgcn_mfma_f32_16x16x32_bf16(af, w0f[(size_t)((kt+4)*8 + nt)*64 + lane], accQ[nt], 0, 0, 0);
        }
    }
    #pragma unroll
    for (int nt = 0; nt < 8; nt++) {
        int col = nt*16 + l15;
        #pragma unroll
        for (int j = 0; j < 4; j++) {
            long long r = nbase + lg*4 + j;
            if (r < N_NODES) {
                P[r*128 + col] = f2bf(accP[nt][j]);
                Q[r*128 + col] = f2bf(accQ[nt][j]);
            }
        }
    }
}

// ---------------------------------------------------------------------------
// Edge kernel (CSR-sorted): 512 threads (8 waves), 128 edges/block.
// Occupancy-tuned for 3 blocks/CU (24 waves): VGPR pinned <=64 via
// __launch_bounds__(512,8); LDS = 50.0KB = pq tiles (34.8KB, pad 136)
// + HALF of W1 (kt 0-1, 16KB). W0c and W1 kt 2-3 B-frags read from
// global/L2 (shared by all blocks). Wide dwordx4 epilogue stores (r9).
// ---------------------------------------------------------------------------
template<bool EAF32>
__global__ __launch_bounds__(512, 8)
void edge_kernel(const short* __restrict__ P,
                 const short* __restrict__ Q,
                 const void* __restrict__ ea_in_v,
                 short* __restrict__ ea_out,
                 const int* __restrict__ psrc,
                 const int* __restrict__ ptgt,
                 const int* __restrict__ elist,
                 const short* __restrict__ w0p,
                 const float* __restrict__ b0,
                 const float* __restrict__ b1,
                 const float* __restrict__ lng,
                 const float* __restrict__ lnb) {
    __shared__ __align__(16) short w1lds[8192];      // 16KB: W1 kt 0-1
    __shared__ __align__(16) short pq[8][16][136];   // 34816B per-wave tiles
    const int tid  = threadIdx.x;
    const int wave = tid >> 6, lane = tid & 63;
    const int l15  = lane & 15, lg = lane >> 4;
    const long long ebase = (long long)blockIdx.x * 128 + wave * 16;
    const long long arow  = ebase + l15;
    const long long arc   = arow < N_EDGES ? arow : (N_EDGES - 1);
    const float* eaf = (const float*)ea_in_v;
    const short* eab = (const short*)ea_in_v;
    const bf16x8* w0c = (const bf16x8*)(w0p + 32768);   // W0c frags (L2)
    const bf16x8* w1g = (const bf16x8*)(w0p + 49152);   // W1 frags (L2, kt 2-3)

    // --- issue W1 kt 0-1 loads (16KB contiguous at w0p+49152) ---
    const short* w1src = w0p + 49152;
    bf16x8 wtmp[2];
    #pragma unroll
    for (int it = 0; it < 2; it++)
        wtmp[it] = *(const bf16x8*)(w1src + it*4096 + tid*8);

    // --- per-wave gather: P[psrc]+Q[ptgt] summed in registers ---
    {
        const int c8 = (lane & 7) * 16;        // 32B column chunk (shorts)
        #pragma unroll
        for (int pass = 0; pass < 2; pass++) {
            int rr = (lane >> 3) + pass * 8;
            long long e = ebase + rr;
            if (e >= N_EDGES) e = N_EDGES - 1;
            long long s = psrc[e], t = ptgt[e];
            bf16x8 p0 = *(const bf16x8*)(P + s*128 + c8);
            bf16x8 p1 = *(const bf16x8*)(P + s*128 + c8 + 8);
            bf16x8 q0 = *(const bf16x8*)(Q + t*128 + c8);
            bf16x8 q1 = *(const bf16x8*)(Q + t*128 + c8 + 8);
            bf16x8 u0, u1;
            #pragma unroll
            for (int k = 0; k < 8; k++) {
                u0[k] = f2bf(bf2f(p0[k]) + bf2f(q0[k]));
                u1[k] = f2bf(bf2f(p1[k]) + bf2f(q1[k]));
            }
            *(bf16x8*)&pq[wave][rr][c8]     = u0;
            *(bf16x8*)&pq[wave][rr][c8 + 8] = u1;
        }
    }

    // --- load ea fragments (A-operand + residual) ---
    bf16x8 eafrag[4];
    #pragma unroll
    for (int kt = 0; kt < 4; kt++) {
        if (EAF32) {
            long long orig = elist[arc];          // one-time scatter at iter 0
            const float* ap = eaf + orig*128 + kt*32 + lg*8;
            float4 f0 = *(const float4*)ap;
            float4 f1 = *(const float4*)(ap + 4);
            bf16x8 af;
            af[0]=f2bf(f0.x); af[1]=f2bf(f0.y); af[2]=f2bf(f0.z); af[3]=f2bf(f0.w);
            af[4]=f2bf(f1.x); af[5]=f2bf(f1.y); af[6]=f2bf(f1.z); af[7]=f2bf(f1.w);
            eafrag[kt] = af;
        } else {
            eafrag[kt] = *(const bf16x8*)(eab + arc*128 + kt*32 + lg*8);
        }
    }

    // --- commit W1 half to LDS, block barrier (the only one) ---
    #pragma unroll
    for (int it = 0; it < 2; it++)
        *(bf16x8*)&w1lds[it*4096 + tid*8] = wtmp[it];
    __syncthreads();

    // --- layer0: ea @ W0c (B-frags from global/L2) ---
    f32x4 acc[8] = {};
    #pragma unroll
    for (int kt = 0; kt < 4; kt++) {
        #pragma unroll
        for (int nt = 0; nt < 8; nt++) {
            bf16x8 bfr = w0c[(size_t)(kt*8 + nt)*64 + lane];
            acc[nt] = __builtin_amdgcn_mfma_f32_16x16x32_bf16(eafrag[kt], bfr, acc[nt], 0, 0, 0);
        }
    }

    // --- bias + PQ add + ELU; hidden in place (lane-owned) ---
    #pragma unroll
    for (int nt = 0; nt < 8; nt++) {
        int col = nt*16 + l15;
        float bb = b0[col];
        #pragma unroll
        for (int j = 0; j < 4; j++) {
            int r = lg*4 + j;
            float v = acc[nt][j] + bb + bf2f(pq[wave][r][col]);
            v = v > 0.f ? v : (__expf(v) - 1.f);
            pq[wave][r][col] = f2bf(v);
        }
    }
    LGKM0();   // hidden visible to all lanes of this wave

    // --- layer1: hid @ W1 (kt 0-1 from LDS, kt 2-3 from global/L2) ---
    f32x4 acc2[8] = {};
    #pragma unroll
    for (int kt = 0; kt < 4; kt++) {
        bf16x8 af = *(const bf16x8*)&pq[wave][l15][kt*32 + lg*8];
        #pragma unroll
        for (int nt = 0; nt < 8; nt++) {
            bf16x8 bfr;
            if (kt < 2) bfr = *(const bf16x8*)&w1lds[((kt*8 + nt)*64 + lane)*8];
            else        bfr = w1g[(size_t)(kt*8 + nt)*64 + lane];
            acc2[nt] = __builtin_amdgcn_mfma_f32_16x16x32_bf16(af, bfr, acc2[nt], 0, 0, 0);
        }
    }
    LGKM0();   // hidden ds_reads drained -> tile reusable

    // --- stage ea fragments (residual source) ---
    #pragma unroll
    for (int kt = 0; kt < 4; kt++)
        *(bf16x8*)&pq[wave][l15][kt*32 + lg*8] = eafrag[kt];
    LGKM0();

    // --- residual (LDS) + LayerNorm ---
    float t[8][4];
    #pragma unroll
    for (int nt = 0; nt < 8; nt++) {
        int col = nt*16 + l15;
        float bb = b1[col];
        #pragma unroll
        for (int j = 0; j < 4; j++) {
            int r = lg*4 + j;
            t[nt][j] = acc2[nt][j] + bb + bf2f(pq[wave][r][col]);
        }
    }
    LGKM0();   // all residual reads done -> tile reusable for output staging

    #pragma unroll
    for (int j = 0; j < 4; j++) {
        float s = 0.f;
        #pragma unroll
        for (int nt = 0; nt < 8; nt++) s += t[nt][j];
        #pragma unroll
        for (int m = 1; m < 16; m <<= 1) s += __shfl_xor(s, m);
        float mean = s * (1.0f / 128.0f);
        float s2 = 0.f;
        #pragma unroll
        for (int nt = 0; nt < 8; nt++) { float d = t[nt][j] - mean; s2 += d*d; }
        #pragma unroll
        for (int m = 1; m < 16; m <<= 1) s2 += __shfl_xor(s2, m);
        float rstd = rsqrtf(s2 * (1.0f / 128.0f) + 1e-5f);
        int r = lg*4 + j;
        #pragma unroll
        for (int nt = 0; nt < 8; nt++) {
            int col = nt*16 + l15;
            pq[wave][r][col] = f2bf((t[nt][j] - mean) * rstd * lng[col] + lnb[col]);
        }
    }
    LGKM0();   // LN output staged (wave-local)

    // --- wide coalesced store: wave streams its 16 rows (4KB) ---
    #pragma unroll
    for (int k = 0; k < 4; k++) {
        int row = k*4 + (lane >> 4);
        long long erow = ebase + row;
        bf16x8 vv = *(const bf16x8*)&pq[wave][row][l15*8];
        if (erow < N_EDGES)
            *(bf16x8*)&ea_out[erow*128 + l15*8] = vv;
    }
}

// ---------------------------------------------------------------------------
// Aggregation: one wave per node; ea rows for node n are CONTIGUOUS
// [off[n], off[n+1]) in the permuted layout -> pure streaming read.
// ---------------------------------------------------------------------------
__global__ __launch_bounds__(256)
void agg_kernel(const short* __restrict__ ea,
                const int* __restrict__ off,
                short* __restrict__ aggb) {
    const int wid  = (blockIdx.x * 256 + threadIdx.x) >> 6;
    const int lane = threadIdx.x & 63;
    if (wid >= N_NODES) return;
    const int o0 = off[wid], o1 = off[wid + 1];
    float s0 = 0.f, s1 = 0.f;
    for (int i = o0; i < o1; i++) {
        unsigned int v = *(const unsigned int*)(ea + (long long)i*128 + lane*2);
        s0 += __uint_as_float(v << 16);
        s1 += __uint_as_float(v & 0xFFFF0000u);
    }
    float inv = (o1 > o0) ? 1.f / (float)(o1 - o0) : 0.f;
    short2 w;
    w.x = f2bf(s0 * inv);
    w.y = f2bf(s1 * inv);
    *(short2*)(aggb + (long long)wid*128 + lane*2) = w;
}

// ---------------------------------------------------------------------------
// Node kernel + fused P/Q production for the NEXT iteration.
// ---------------------------------------------------------------------------
template<bool MAKEPQ>
__global__ __launch_bounds__(256)
void node_kernel(const float* __restrict__ x_in,
                 float* __restrict__ x_out,
                 const short* __restrict__ aggb,
                 const short* __restrict__ w0p,
                 const short* __restrict__ w1p,
                 const short* __restrict__ wnext,   // next iter edge W0a/b frags
                 short* __restrict__ P,
                 short* __restrict__ Q,
                 const float* __restrict__ b0,
                 const float* __restrict__ b1,
                 const float* __restrict__ lng,
                 const float* __restrict__ lnb) {
    __shared__ __align__(16) short hid[4][16][140];
    const int tid  = threadIdx.x;
    const int wave = tid >> 6, lane = tid & 63;
    const int l15  = lane & 15, lg = lane >> 4;
    const long long nbase = (long long)blockIdx.x * 64 + wave * 16;
    long long arow = nbase + l15;
    if (arow >= N_NODES) arow = N_NODES - 1;

    f32x4 acc[8] = {};
    const bf16x8* w0f = (const bf16x8*)w0p;
    #pragma unroll
    for (int kt = 0; kt < 8; kt++) {
        int k0 = kt*32 + lg*8;
        bf16x8 af;
        if (k0 < 128) {
            const float* ap = x_in + arow*128 + k0;
            float4 f0 = *(const float4*)ap;
            float4 f1 = *(const float4*)(ap + 4);
            af[0]=f2bf(f0.x); af[1]=f2bf(f0.y); af[2]=f2bf(f0.z); af[3]=f2bf(f0.w);
            af[4]=f2bf(f1.x); af[5]=f2bf(f1.y); af[6]=f2bf(f1.z); af[7]=f2bf(f1.w);
        } else {
            af = *(const bf16x8*)(aggb + arow*128 + (k0 - 128));
        }
        #pragma unroll
        for (int nt = 0; nt < 8; nt++) {
            bf16x8 bfr = w0f[(size_t)(kt*8 + nt)*64 + lane];
            acc[nt] = __builtin_amdgcn_mfma_f32_16x16x32_bf16(af, bfr, acc[nt], 0, 0, 0);
        }
    }
    #pragma unroll
    for (int nt = 0; nt < 8; nt++) {
        int col = nt*16 + l15;
        float bb = b0[col];
        #pragma unroll
        for (int j = 0; j < 4; j++) {
            float v = acc[nt][j] + bb;
            v = v > 0.f ? v : (__expf(v) - 1.f);
            hid[wave][lg*4 + j][col] = f2bf(v);
        }
    }
    LGKM0();   // hid writes complete (wave-local)

    f32x4 acc2[8] = {};
    const bf16x8* w1f = (const bf16x8*)w1p;
    #pragma unroll
    for (int kt = 0; kt < 4; kt++) {
        bf16x8 af = *(const bf16x8*)&hid[wave][l15][kt*32 + lg*8];
        #pragma unroll
        for (int nt = 0; nt < 8; nt++) {
            bf16x8 bfr = w1f[(size_t)(kt*8 + nt)*64 + lane];
            acc2[nt] = __builtin_amdgcn_mfma_f32_16x16x32_bf16(af, bfr, acc2[nt], 0, 0, 0);
        }
    }
    float t[8][4];
    #pragma unroll
    for (int nt = 0; nt < 8; nt++) {
        int col = nt*16 + l15;
        float bb = b1[col];
        #pragma unroll
        for (int j = 0; j < 4; j++) {
            long long nrow = nbase + lg*4 + j;
            long long nrc  = nrow < N_NODES ? nrow : (N_NODES - 1);
            t[nt][j] = acc2[nt][j] + bb + x_in[nrc*128 + col];
        }
    }
    float xo[8][4];
    #pragma unroll
    for (int j = 0; j < 4; j++) {
        float s = 0.f;
        #pragma unroll
        for (int nt = 0; nt < 8; nt++) s += t[nt][j];
        #pragma unroll
        for (int m = 1; m < 16; m <<= 1) s += __shfl_xor(s, m);
        float mean = s * (1.0f / 128.0f);
        float s2 = 0.f;
        #pragma unroll
        for (int nt = 0; nt < 8; nt++) { float d = t[nt][j] - mean; s2 += d*d; }
        #pragma unroll
        for (int m = 1; m < 16; m <<= 1) s2 += __shfl_xor(s2, m);
        float rstd = rsqrtf(s2 * (1.0f / 128.0f) + 1e-5f);
        long long nrow = nbase + lg*4 + j;
        #pragma unroll
        for (int nt = 0; nt < 8; nt++) {
            int col = nt*16 + l15;
            float v = (t[nt][j] - mean) * rstd * lng[col] + lnb[col];
            xo[nt][j] = v;
            if (nrow < N_NODES) x_out[nrow*128 + col] = v;
        }
    }

    if (MAKEPQ) {
        LGKM0();   // layer1 ds_reads drained
        #pragma unroll
        for (int nt = 0; nt < 8; nt++) {
            int col = nt*16 + l15;
            #pragma unroll
            for (int j = 0; j < 4; j++)
                hid[wave][lg*4 + j][col] = f2bf(xo[nt][j]);
        }
        LGKM0();

        const bf16x8* wn = (const bf16x8*)wnext;
        {
            f32x4 accP[8] = {};
            #pragma unroll
            for (int kt = 0; kt < 4; kt++) {
                bf16x8 af = *(const bf16x8*)&hid[wave][l15][kt*32 + lg*8];
                #pragma unroll
                for (int nt = 0; nt < 8; nt++)
                    accP[nt] = __builtin_amdgcn_mfma_f32_16x16x32_bf16(af, wn[(size_t)(kt*8 + nt)*64 + lane], accP[nt], 0, 0, 0);
            }
            #pragma unroll
            for (int nt = 0; nt < 8; nt++) {
                int col = nt*16 + l15;
                #pragma unroll
                for (int j = 0; j < 4; j++) {
                    long long r = nbase + lg*4 + j;
                    if (r < N_NODES) P[r*128 + col] = f2bf(accP[nt][j]);
                }
            }
        }
        {
            f32x4 accQ[8] = {};
            #pragma unroll
            for (int kt = 0; kt < 4; kt++) {
                bf16x8 af = *(const bf16x8*)&hid[wave][l15][kt*32 + lg*8];
                #pragma unroll
                for (int nt = 0; nt < 8; nt++)
                    accQ[nt] = __builtin_amdgcn_mfma_f32_16x16x32_bf16(af, wn[(size_t)((kt+4)*8 + nt)*64 + lane], accQ[nt], 0, 0, 0);
            }
            #pragma unroll
            for (int nt = 0; nt < 8; nt++) {
                int col = nt*16 + l15;
                #pragma unroll
                for (int j = 0; j < 4; j++) {
                    long long r = nbase + lg*4 + j;
                    if (r < N_NODES) Q[r*128 + col] = f2bf(accQ[nt][j]);
                }
            }
        }
    }
}

extern "C" void kernel_launch(void* const* d_in, const int* in_sizes, int n_in,
                              void* d_out, int out_size, void* d_ws, size_t ws_size,
                              hipStream_t stream) {
    const float* x_in   = (const float*)d_in[0];
    const int*   eidx   = (const int*)d_in[1];
    const float* ea_in0 = (const float*)d_in[2];
    const float* ew0  = (const float*)d_in[5];
    const float* eb0  = (const float*)d_in[6];
    const float* ew1  = (const float*)d_in[7];
    const float* eb1  = (const float*)d_in[8];
    const float* elng = (const float*)d_in[9];
    const float* elnb = (const float*)d_in[10];
    const float* nw0  = (const float*)d_in[11];
    const float* nb0  = (const float*)d_in[12];
    const float* nw1  = (const float*)d_in[13];
    const float* nb1  = (const float*)d_in[14];
    const float* nlng = (const float*)d_in[15];
    const float* nlnb = (const float*)d_in[16];
    const int* srcI = eidx;
    const int* tgtI = eidx + N_EDGES;

    // ---- workspace layout (bytes) ----
    char* ws = (char*)d_ws;
    size_t o = 0;
    short* ea_bf  = (short*)(ws + o); o += (size_t)N_EDGES * 128 * 2;       // 153.6 MB (permuted)
    short* Pb     = (short*)(ws + o); o += (size_t)N_NODES * 128 * 2;       // 25.6 MB
    short* Qb     = (short*)(ws + o); o += (size_t)N_NODES * 128 * 2;       // 25.6 MB
    short* aggb   = (short*)(ws + o); o += (size_t)N_NODES * 128 * 2;       // 25.6 MB
    short* wpack  = (short*)(ws + o); o += (size_t)NMP * 114688 * 2;        // 0.92 MB
    int*   deg    = (int*)(ws + o);   o += (size_t)N_NODES * 4;
    int*   offA   = (int*)(ws + o);   o += (size_t)(N_NODES + 1) * 4;
    int*   cursor = (int*)(ws + o);   o += (size_t)N_NODES * 4;
    int*   bsum   = (int*)(ws + o);   o += (size_t)NB_SCAN * 4;
    int*   bbase  = (int*)(ws + o);   o += (size_t)NB_SCAN * 4;
    int*   elist  = (int*)(ws + o);   o += (size_t)N_EDGES * 4;
    int*   psrc   = (int*)(ws + o);   o += (size_t)N_EDGES * 4;
    int*   ptgt   = (int*)(ws + o);   o += (size_t)N_EDGES * 4;
    float* xbuf   = (float*)d_out;

    // ---- one-time: weight pack + CSR + permuted index arrays ----
    pack_weights<<<(NMP * 14336 + 255) / 256, 256, 0, stream>>>(ew0, ew1, nw0, nw1, wpack);
    hipMemsetAsync(deg, 0, (size_t)N_NODES * 4, stream);
    deg_count<<<(N_EDGES + 255) / 256, 256, 0, stream>>>(tgtI, deg);
    scan_reduce<<<NB_SCAN, 256, 0, stream>>>(deg, bsum);
    scan_top<<<1, 64, 0, stream>>>(bsum, bbase, offA);
    scan_apply<<<NB_SCAN, 256, 0, stream>>>(deg, bbase, offA, cursor);
    fill_csr<<<(N_EDGES + 255) / 256, 256, 0, stream>>>(tgtI, cursor, elist);
    build_perm<<<(N_EDGES + 255) / 256, 256, 0, stream>>>(srcI, tgtI, elist, psrc, ptgt);

    const int ngrid = (N_NODES + 63) / 64;
    const int egrid = (N_EDGES + 127) / 128;
    // iter-0 P/Q from input x
    xform_kernel<<<ngrid, 256, 0, stream>>>(x_in, Pb, Qb, wpack);

    for (int i = 0; i < NMP; i++) {
        const float* xg = (i == 0) ? x_in : xbuf;
        const short* wp = wpack + (size_t)i * 114688;
        const short* wnext = wpack + (size_t)(i + 1) * 114688;   // unused when i==3
        if (i == 0) {
            edge_kernel<true><<<egrid, 512, 0, stream>>>(
                Pb, Qb, (const void*)ea_in0, ea_bf, psrc, ptgt, elist,
                wp + 0,
                eb0 + i * 128, eb1 + i * 128, elng + i * 128, elnb + i * 128);
        } else {
            edge_kernel<false><<<egrid, 512, 0, stream>>>(
                Pb, Qb, (const void*)ea_bf, ea_bf, psrc, ptgt, elist,
                wp + 0,
                eb0 + i * 128, eb1 + i * 128, elng + i * 128, elnb + i * 128);
        }
        agg_kernel<<<(N_NODES * 64 + 255) / 256, 256, 0, stream>>>(ea_bf, offA, aggb);
        if (i < NMP - 1) {
            node_kernel<true><<<ngrid, 256, 0, stream>>>(
                xg, xbuf, aggb,
                wp + 65536, wp + 98304, wnext, Pb, Qb,
                nb0 + i * 128, nb1 + i * 128, nlng + i * 128, nlnb + i * 128);
        } else {
            node_kernel<false><<<ngrid, 256, 0, stream>>>(
                xg, xbuf, aggb,
                wp + 65536, wp + 98304, wnext, Pb, Qb,
                nb0 + i * 128, nb1 + i * 128, nlng + i * 128, nlnb + i * 128);
        }
    }
}

// Round 14
// 1266.829 us; speedup vs baseline: 1.1627x; 1.0145x over previous
//
#include <hip/hip_runtime.h>
#include <hip/hip_bf16.h>

#define N_NODES 100000
#define N_EDGES 600000
#define NMP     4
#define NB_SCAN 391   // ceil(N_NODES/256)

typedef __attribute__((ext_vector_type(8))) short bf16x8;
typedef __attribute__((ext_vector_type(4))) float f32x4;

#define LGKM0() asm volatile("s_waitcnt lgkmcnt(0)" ::: "memory")

__device__ __forceinline__ short f2bf(float f) {
    unsigned int u = __float_as_uint(f);
    u += 0x7FFFu + ((u >> 16) & 1u);      // round-to-nearest-even
    return (short)(u >> 16);
}
__device__ __forceinline__ float bf2f(short s) {
    return __uint_as_float(((unsigned int)(unsigned short)s) << 16);
}

// ---------------------------------------------------------------------------
// Pack weights [K][128] f32 -> MFMA B-fragment order bf16:
// frag(kt,nt,lane)[j] = W[kt*32 + (lane>>4)*8 + j][nt*16 + (lane&15)]
// Per-iter packed layout (elems): edge_w0 @0 (49152), edge_w1 @49152 (16384),
// node_w0 @65536 (32768), node_w1 @98304 (16384); iter stride 114688.
// W0c (ea part, kt 8..11) = elems [32768,49152); W1 = [49152,65536).
// ---------------------------------------------------------------------------
__global__ void pack_weights(const float* __restrict__ ew0, const float* __restrict__ ew1,
                             const float* __restrict__ nw0, const float* __restrict__ nw1,
                             short* __restrict__ out) {
    int t = blockIdx.x * blockDim.x + threadIdx.x;
    if (t >= NMP * 14336) return;
    int it = t / 14336;
    int r  = t % 14336;
    const float* W; int obase;
    if (r < 6144)       { W = ew0 + (size_t)it*384*128; obase = 0;     }
    else if (r < 8192)  { W = ew1 + (size_t)it*128*128; obase = 49152; r -= 6144;  }
    else if (r < 12288) { W = nw0 + (size_t)it*256*128; obase = 65536; r -= 8192;  }
    else                { W = nw1 + (size_t)it*128*128; obase = 98304; r -= 12288; }
    int kt   = r >> 9;
    int rem  = r & 511;
    int nt   = rem >> 6;
    int lane = rem & 63;
    short* o = out + (size_t)it*114688 + obase + ((size_t)(kt*8 + nt)*64 + lane)*8;
    int kbase = kt*32 + (lane >> 4)*8;
    int n     = nt*16 + (lane & 15);
    #pragma unroll
    for (int j = 0; j < 8; j++) o[j] = f2bf(W[(size_t)(kbase + j)*128 + n]);
}

// ------------------------- CSR build (once per launch) ----------------------
__global__ void deg_count(const int* __restrict__ tgt, int* __restrict__ deg) {
    int e = blockIdx.x * blockDim.x + threadIdx.x;
    if (e < N_EDGES) atomicAdd(&deg[tgt[e]], 1);
}

__global__ void scan_reduce(const int* __restrict__ deg, int* __restrict__ bsum) {
    __shared__ int sh[256];
    int i = blockIdx.x * 256 + threadIdx.x;
    sh[threadIdx.x] = (i < N_NODES) ? deg[i] : 0;
    __syncthreads();
    for (int d = 128; d > 0; d >>= 1) {
        if (threadIdx.x < d) sh[threadIdx.x] += sh[threadIdx.x + d];
        __syncthreads();
    }
    if (threadIdx.x == 0) bsum[blockIdx.x] = sh[0];
}

__global__ void scan_top(const int* __restrict__ bsum, int* __restrict__ bbase,
                         int* __restrict__ off) {
    if (threadIdx.x == 0 && blockIdx.x == 0) {
        int run = 0;
        for (int b = 0; b < NB_SCAN; b++) { bbase[b] = run; run += bsum[b]; }
        off[N_NODES] = run;
    }
}

__global__ void scan_apply(const int* __restrict__ deg, const int* __restrict__ bbase,
                           int* __restrict__ off, int* __restrict__ cursor) {
    __shared__ int sh[256];
    int i = blockIdx.x * 256 + threadIdx.x;
    int v = (i < N_NODES) ? deg[i] : 0;
    sh[threadIdx.x] = v;
    __syncthreads();
    int acc = v;
    for (int d = 1; d < 256; d <<= 1) {
        int t = (threadIdx.x >= d) ? sh[threadIdx.x - d] : 0;
        __syncthreads();
        acc += t;
        sh[threadIdx.x] = acc;
        __syncthreads();
    }
    if (i < N_NODES) {
        int o = bbase[blockIdx.x] + acc - v;   // exclusive
        off[i] = o;
        cursor[i] = o;
    }
}

__global__ void fill_csr(const int* __restrict__ tgt, int* __restrict__ cursor,
                         int* __restrict__ elist) {
    int e = blockIdx.x * blockDim.x + threadIdx.x;
    if (e < N_EDGES) {
        int p = atomicAdd(&cursor[tgt[e]], 1);
        elist[p] = e;
    }
}

// psrc/ptgt: src/tgt per SORTED edge position
__global__ void build_perm(const int* __restrict__ srcI, const int* __restrict__ tgtI,
                           const int* __restrict__ elist,
                           int* __restrict__ psrc, int* __restrict__ ptgt) {
    int k = blockIdx.x * blockDim.x + threadIdx.x;
    if (k < N_EDGES) {
        int e = elist[k];
        psrc[k] = srcI[e];
        ptgt[k] = tgtI[e];
    }
}

// ---------------------------------------------------------------------------
// xform: P = x@W0a, Q = x@W0b  (bf16 outputs, [N][128] each) — iter 0 only.
// ---------------------------------------------------------------------------
__global__ __launch_bounds__(256)
void xform_kernel(const float* __restrict__ x_in,
                  short* __restrict__ P, short* __restrict__ Q,
                  const short* __restrict__ w0p) {
    const int tid  = threadIdx.x;
    const int wave = tid >> 6, lane = tid & 63;
    const int l15  = lane & 15, lg = lane >> 4;
    const long long nbase = (long long)blockIdx.x * 64 + wave * 16;
    long long arow = nbase + l15;
    if (arow >= N_NODES) arow = N_NODES - 1;

    f32x4 accP[8] = {}, accQ[8] = {};
    const bf16x8* w0f = (const bf16x8*)w0p;
    #pragma unroll
    for (int kt = 0; kt < 4; kt++) {
        const float* ap = x_in + arow*128 + kt*32 + lg*8;
        float4 f0 = *(const float4*)ap;
        float4 f1 = *(const float4*)(ap + 4);
        bf16x8 af;
        af[0]=f2bf(f0.x); af[1]=f2bf(f0.y); af[2]=f2bf(f0.z); af[3]=f2bf(f0.w);
        af[4]=f2bf(f1.x); af[5]=f2bf(f1.y); af[6]=f2bf(f1.z); af[7]=f2bf(f1.w);
        #pragma unroll
        for (int nt = 0; nt < 8; nt++) {
            accP[nt] = __builtin_amdgcn_mfma_f32_16x16x32_bf16(af, w0f[(size_t)(kt*8 + nt)*64 + lane], accP[nt], 0, 0, 0);
            accQ[nt] = __builtin_amdgcn_mfma_f32_16x16x32_bf16(af, w0f[(size_t)((kt+4)*8 + nt)*64 + lane], accQ[nt], 0, 0, 0);
        }
    }
    #pragma unroll
    for (int nt = 0; nt < 8; nt++) {
        int col = nt*16 + l15;
        #pragma unroll
        for (int j = 0; j < 4; j++) {
            long long r = nbase + lg*4 + j;
            if (r < N_NODES) {
                P[r*128 + col] = f2bf(accP[nt][j]);
                Q[r*128 + col] = f2bf(accQ[nt][j]);
            }
        }
    }
}

// ---------------------------------------------------------------------------
// Edge kernel — EXACT r9 structure (best measured: 192 us):
// 512 threads (8 waves), 128 edges/block, CSR-sorted edges.
// LDS 67.8KB -> 2 blocks/CU: W1 staged in LDS (32KB), W0c B-frags from
// global/L2. Wide dwordx4 epilogue stores via per-wave pq tile staging.
// ---------------------------------------------------------------------------
template<bool EAF32>
__global__ __launch_bounds__(512)
void edge_kernel(const short* __restrict__ P,
                 const short* __restrict__ Q,
                 const void* __restrict__ ea_in_v,
                 short* __restrict__ ea_out,
                 const int* __restrict__ psrc,
                 const int* __restrict__ ptgt,
                 const int* __restrict__ elist,
                 const short* __restrict__ w0p,
                 const float* __restrict__ b0,
                 const float* __restrict__ b1,
                 const float* __restrict__ lng,
                 const float* __restrict__ lnb) {
    __shared__ __align__(16) short w1lds[16384];     // 32KB: W1
    __shared__ __align__(16) short pq[8][16][140];   // 35840B per-wave tiles
    const int tid  = threadIdx.x;
    const int wave = tid >> 6, lane = tid & 63;
    const int l15  = lane & 15, lg = lane >> 4;
    const long long ebase = (long long)blockIdx.x * 128 + wave * 16;
    const long long arow  = ebase + l15;
    const long long arc   = arow < N_EDGES ? arow : (N_EDGES - 1);
    const float* eaf = (const float*)ea_in_v;
    const short* eab = (const short*)ea_in_v;
    const bf16x8* w0c = (const bf16x8*)(w0p + 32768);   // W0c frags via L1/L2

    // --- issue W1 loads (32KB contiguous at w0p+49152) ---
    const short* w1src = w0p + 49152;
    bf16x8 wtmp[4];
    #pragma unroll
    for (int it = 0; it < 4; it++)
        wtmp[it] = *(const bf16x8*)(w1src + it*4096 + tid*8);

    // --- per-wave gather: P[psrc]+Q[ptgt] summed in registers ---
    {
        const int c8 = (lane & 7) * 16;        // 32B column chunk (shorts)
        #pragma unroll
        for (int pass = 0; pass < 2; pass++) {
            int rr = (lane >> 3) + pass * 8;
            long long e = ebase + rr;
            if (e >= N_EDGES) e = N_EDGES - 1;
            long long s = psrc[e], t = ptgt[e];
            bf16x8 p0 = *(const bf16x8*)(P + s*128 + c8);
            bf16x8 p1 = *(const bf16x8*)(P + s*128 + c8 + 8);
            bf16x8 q0 = *(const bf16x8*)(Q + t*128 + c8);
            bf16x8 q1 = *(const bf16x8*)(Q + t*128 + c8 + 8);
            bf16x8 u0, u1;
            #pragma unroll
            for (int k = 0; k < 8; k++) {
                u0[k] = f2bf(bf2f(p0[k]) + bf2f(q0[k]));
                u1[k] = f2bf(bf2f(p1[k]) + bf2f(q1[k]));
            }
            *(bf16x8*)&pq[wave][rr][c8]     = u0;
            *(bf16x8*)&pq[wave][rr][c8 + 8] = u1;
        }
    }

    // --- load ea fragments (A-operand + residual) ---
    bf16x8 eafrag[4];
    #pragma unroll
    for (int kt = 0; kt < 4; kt++) {
        if (EAF32) {
            long long orig = elist[arc];          // one-time scatter at iter 0
            const float* ap = eaf + orig*128 + kt*32 + lg*8;
            float4 f0 = *(const float4*)ap;
            float4 f1 = *(const float4*)(ap + 4);
            bf16x8 af;
            af[0]=f2bf(f0.x); af[1]=f2bf(f0.y); af[2]=f2bf(f0.z); af[3]=f2bf(f0.w);
            af[4]=f2bf(f1.x); af[5]=f2bf(f1.y); af[6]=f2bf(f1.z); af[7]=f2bf(f1.w);
            eafrag[kt] = af;
        } else {
            eafrag[kt] = *(const bf16x8*)(eab + arc*128 + kt*32 + lg*8);
        }
    }

    // --- commit W1 to LDS, block barrier (the only one) ---
    #pragma unroll
    for (int it = 0; it < 4; it++)
        *(bf16x8*)&w1lds[it*4096 + tid*8] = wtmp[it];
    __syncthreads();

    // --- layer0: ea @ W0c (B-frags from global/L1) ---
    f32x4 acc[8] = {};
    #pragma unroll
    for (int kt = 0; kt < 4; kt++) {
        #pragma unroll
        for (int nt = 0; nt < 8; nt++) {
            bf16x8 bfr = w0c[(size_t)(kt*8 + nt)*64 + lane];
            acc[nt] = __builtin_amdgcn_mfma_f32_16x16x32_bf16(eafrag[kt], bfr, acc[nt], 0, 0, 0);
        }
    }

    // --- bias + PQ add + ELU; hidden in place (lane-owned) ---
    #pragma unroll
    for (int nt = 0; nt < 8; nt++) {
        int col = nt*16 + l15;
        float bb = b0[col];
        #pragma unroll
        for (int j = 0; j < 4; j++) {
            int r = lg*4 + j;
            float v = acc[nt][j] + bb + bf2f(pq[wave][r][col]);
            v = v > 0.f ? v : (__expf(v) - 1.f);
            pq[wave][r][col] = f2bf(v);
        }
    }
    LGKM0();   // hidden visible to all lanes of this wave

    // --- layer1: hid @ W1 (B-frags from LDS) ---
    f32x4 acc2[8] = {};
    #pragma unroll
    for (int kt = 0; kt < 4; kt++) {
        bf16x8 af = *(const bf16x8*)&pq[wave][l15][kt*32 + lg*8];
        #pragma unroll
        for (int nt = 0; nt < 8; nt++) {
            bf16x8 bfr = *(const bf16x8*)&w1lds[((kt*8 + nt)*64 + lane)*8];
            acc2[nt] = __builtin_amdgcn_mfma_f32_16x16x32_bf16(af, bfr, acc2[nt], 0, 0, 0);
        }
    }
    LGKM0();   // hidden ds_reads drained -> tile reusable

    // --- stage ea fragments (residual source) ---
    #pragma unroll
    for (int kt = 0; kt < 4; kt++)
        *(bf16x8*)&pq[wave][l15][kt*32 + lg*8] = eafrag[kt];
    LGKM0();

    // --- residual (LDS) + LayerNorm ---
    float t[8][4];
    #pragma unroll
    for (int nt = 0; nt < 8; nt++) {
        int col = nt*16 + l15;
        float bb = b1[col];
        #pragma unroll
        for (int j = 0; j < 4; j++) {
            int r = lg*4 + j;
            t[nt][j] = acc2[nt][j] + bb + bf2f(pq[wave][r][col]);
        }
    }
    LGKM0();   // all residual reads done -> tile reusable for output staging

    #pragma unroll
    for (int j = 0; j < 4; j++) {
        float s = 0.f;
        #pragma unroll
        for (int nt = 0; nt < 8; nt++) s += t[nt][j];
        #pragma unroll
        for (int m = 1; m < 16; m <<= 1) s += __shfl_xor(s, m);
        float mean = s * (1.0f / 128.0f);
        float s2 = 0.f;
        #pragma unroll
        for (int nt = 0; nt < 8; nt++) { float d = t[nt][j] - mean; s2 += d*d; }
        #pragma unroll
        for (int m = 1; m < 16; m <<= 1) s2 += __shfl_xor(s2, m);
        float rstd = rsqrtf(s2 * (1.0f / 128.0f) + 1e-5f);
        int r = lg*4 + j;
        #pragma unroll
        for (int nt = 0; nt < 8; nt++) {
            int col = nt*16 + l15;
            pq[wave][r][col] = f2bf((t[nt][j] - mean) * rstd * lng[col] + lnb[col]);
        }
    }
    LGKM0();   // LN output staged (wave-local)

    // --- wide coalesced store: wave streams its 16 rows (4KB) ---
    #pragma unroll
    for (int k = 0; k < 4; k++) {
        int row = k*4 + (lane >> 4);
        long long erow = ebase + row;
        bf16x8 vv = *(const bf16x8*)&pq[wave][row][l15*8];
        if (erow < N_EDGES)
            *(bf16x8*)&ea_out[erow*128 + l15*8] = vv;
    }
}

// ---------------------------------------------------------------------------
// Aggregation: one wave per node; ea rows for node n are CONTIGUOUS
// [off[n], off[n+1]) in the permuted layout -> pure streaming read.
// ---------------------------------------------------------------------------
__global__ __launch_bounds__(256)
void agg_kernel(const short* __restrict__ ea,
                const int* __restrict__ off,
                short* __restrict__ aggb) {
    const int wid  = (blockIdx.x * 256 + threadIdx.x) >> 6;
    const int lane = threadIdx.x & 63;
    if (wid >= N_NODES) return;
    const int o0 = off[wid], o1 = off[wid + 1];
    float s0 = 0.f, s1 = 0.f;
    for (int i = o0; i < o1; i++) {
        unsigned int v = *(const unsigned int*)(ea + (long long)i*128 + lane*2);
        s0 += __uint_as_float(v << 16);
        s1 += __uint_as_float(v & 0xFFFF0000u);
    }
    float inv = (o1 > o0) ? 1.f / (float)(o1 - o0) : 0.f;
    short2 w;
    w.x = f2bf(s0 * inv);
    w.y = f2bf(s1 * inv);
    *(short2*)(aggb + (long long)wid*128 + lane*2) = w;
}

// ---------------------------------------------------------------------------
// Node kernel + fused P/Q production. x kept bf16 between iterations:
//   XF32IN : read x from f32 (iter 0) vs bf16 ping-pong buffer
//   XF32OUT: write f32 x to d_out (last iter) vs wide bf16 store
//   MAKEPQ : produce next-iter P/Q from LN'd x staged in hid tile
// ---------------------------------------------------------------------------
template<bool XF32IN, bool XF32OUT, bool MAKEPQ>
__global__ __launch_bounds__(256)
void node_kernel(const float* __restrict__ xf_in,
                 const short* __restrict__ xb_in,
                 float* __restrict__ xf_out,
                 short* __restrict__ xb_out,
                 const short* __restrict__ aggb,
                 const short* __restrict__ w0p,
                 const short* __restrict__ w1p,
                 const short* __restrict__ wnext,
                 short* __restrict__ P,
                 short* __restrict__ Q,
                 const float* __restrict__ b0,
                 const float* __restrict__ b1,
                 const float* __restrict__ lng,
                 const float* __restrict__ lnb) {
    __shared__ __align__(16) short hid[4][16][140];
    const int tid  = threadIdx.x;
    const int wave = tid >> 6, lane = tid & 63;
    const int l15  = lane & 15, lg = lane >> 4;
    const long long nbase = (long long)blockIdx.x * 64 + wave * 16;
    long long arow = nbase + l15;
    if (arow >= N_NODES) arow = N_NODES - 1;

    f32x4 acc[8] = {};
    const bf16x8* w0f = (const bf16x8*)w0p;
    #pragma unroll
    for (int kt = 0; kt < 8; kt++) {
        int k0 = kt*32 + lg*8;
        bf16x8 af;
        if (k0 < 128) {
            if (XF32IN) {
                const float* ap = xf_in + arow*128 + k0;
                float4 f0 = *(const float4*)ap;
                float4 f1 = *(const float4*)(ap + 4);
                af[0]=f2bf(f0.x); af[1]=f2bf(f0.y); af[2]=f2bf(f0.z); af[3]=f2bf(f0.w);
                af[4]=f2bf(f1.x); af[5]=f2bf(f1.y); af[6]=f2bf(f1.z); af[7]=f2bf(f1.w);
            } else {
                af = *(const bf16x8*)(xb_in + arow*128 + k0);
            }
        } else {
            af = *(const bf16x8*)(aggb + arow*128 + (k0 - 128));
        }
        #pragma unroll
        for (int nt = 0; nt < 8; nt++) {
            bf16x8 bfr = w0f[(size_t)(kt*8 + nt)*64 + lane];
            acc[nt] = __builtin_amdgcn_mfma_f32_16x16x32_bf16(af, bfr, acc[nt], 0, 0, 0);
        }
    }
    #pragma unroll
    for (int nt = 0; nt < 8; nt++) {
        int col = nt*16 + l15;
        float bb = b0[col];
        #pragma unroll
        for (int j = 0; j < 4; j++) {
            float v = acc[nt][j] + bb;
            v = v > 0.f ? v : (__expf(v) - 1.f);
            hid[wave][lg*4 + j][col] = f2bf(v);
        }
    }
    LGKM0();   // hid writes complete (wave-local)

    f32x4 acc2[8] = {};
    const bf16x8* w1f = (const bf16x8*)w1p;
    #pragma unroll
    for (int kt = 0; kt < 4; kt++) {
        bf16x8 af = *(const bf16x8*)&hid[wave][l15][kt*32 + lg*8];
        #pragma unroll
        for (int nt = 0; nt < 8; nt++) {
            bf16x8 bfr = w1f[(size_t)(kt*8 + nt)*64 + lane];
            acc2[nt] = __builtin_amdgcn_mfma_f32_16x16x32_bf16(af, bfr, acc2[nt], 0, 0, 0);
        }
    }
    float t[8][4];
    #pragma unroll
    for (int nt = 0; nt < 8; nt++) {
        int col = nt*16 + l15;
        float bb = b1[col];
        #pragma unroll
        for (int j = 0; j < 4; j++) {
            long long nrow = nbase + lg*4 + j;
            long long nrc  = nrow < N_NODES ? nrow : (N_NODES - 1);
            float res = XF32IN ? xf_in[nrc*128 + col] : bf2f(xb_in[nrc*128 + col]);
            t[nt][j] = acc2[nt][j] + bb + res;
        }
    }
    float xo[8][4];
    #pragma unroll
    for (int j = 0; j < 4; j++) {
        float s = 0.f;
        #pragma unroll
        for (int nt = 0; nt < 8; nt++) s += t[nt][j];
        #pragma unroll
        for (int m = 1; m < 16; m <<= 1) s += __shfl_xor(s, m);
        float mean = s * (1.0f / 128.0f);
        float s2 = 0.f;
        #pragma unroll
        for (int nt = 0; nt < 8; nt++) { float d = t[nt][j] - mean; s2 += d*d; }
        #pragma unroll
        for (int m = 1; m < 16; m <<= 1) s2 += __shfl_xor(s2, m);
        float rstd = rsqrtf(s2 * (1.0f / 128.0f) + 1e-5f);
        long long nrow = nbase + lg*4 + j;
        #pragma unroll
        for (int nt = 0; nt < 8; nt++) {
            int col = nt*16 + l15;
            float v = (t[nt][j] - mean) * rstd * lng[col] + lnb[col];
            xo[nt][j] = v;
            if (XF32OUT && nrow < N_NODES) xf_out[nrow*128 + col] = v;
        }
    }

    if (!XF32OUT || MAKEPQ) {
        // stage LN'd x (bf16) into drained hid tile
        LGKM0();   // layer1 ds_reads drained
        #pragma unroll
        for (int nt = 0; nt < 8; nt++) {
            int col = nt*16 + l15;
            #pragma unroll
            for (int j = 0; j < 4; j++)
                hid[wave][lg*4 + j][col] = f2bf(xo[nt][j]);
        }
        LGKM0();
    }

    if (!XF32OUT) {
        // wide coalesced bf16 x store: wave streams its 16 rows (4KB)
        #pragma unroll
        for (int k = 0; k < 4; k++) {
            int row = k*4 + (lane >> 4);
            long long nrow = nbase + row;
            bf16x8 vv = *(const bf16x8*)&hid[wave][row][l15*8];
            if (nrow < N_NODES)
                *(bf16x8*)&xb_out[nrow*128 + l15*8] = vv;
        }
    }

    if (MAKEPQ) {
        const bf16x8* wn = (const bf16x8*)wnext;
        {
            f32x4 accP[8] = {};
            #pragma unroll
            for (int kt = 0; kt < 4; kt++) {
                bf16x8 af = *(const bf16x8*)&hid[wave][l15][kt*32 + lg*8];
                #pragma unroll
                for (int nt = 0; nt < 8; nt++)
                    accP[nt] = __builtin_amdgcn_mfma_f32_16x16x32_bf16(af, wn[(size_t)(kt*8 + nt)*64 + lane], accP[nt], 0, 0, 0);
            }
            #pragma unroll
            for (int nt = 0; nt < 8; nt++) {
                int col = nt*16 + l15;
                #pragma unroll
                for (int j = 0; j < 4; j++) {
                    long long r = nbase + lg*4 + j;
                    if (r < N_NODES) P[r*128 + col] = f2bf(accP[nt][j]);
                }
            }
        }
        {
            f32x4 accQ[8] = {};
            #pragma unroll
            for (int kt = 0; kt < 4; kt++) {
                bf16x8 af = *(const bf16x8*)&hid[wave][l15][kt*32 + lg*8];
                #pragma unroll
                for (int nt = 0; nt < 8; nt++)
                    accQ[nt] = __builtin_amdgcn_mfma_f32_16x16x32_bf16(af, wn[(size_t)((kt+4)*8 + nt)*64 + lane], accQ[nt], 0, 0, 0);
            }
            #pragma unroll
            for (int nt = 0; nt < 8; nt++) {
                int col = nt*16 + l15;
                #pragma unroll
                for (int j = 0; j < 4; j++) {
                    long long r = nbase + lg*4 + j;
                    if (r < N_NODES) Q[r*128 + col] = f2bf(accQ[nt][j]);
                }
            }
        }
    }
}

extern "C" void kernel_launch(void* const* d_in, const int* in_sizes, int n_in,
                              void* d_out, int out_size, void* d_ws, size_t ws_size,
                              hipStream_t stream) {
    const float* x_in   = (const float*)d_in[0];
    const int*   eidx   = (const int*)d_in[1];
    const float* ea_in0 = (const float*)d_in[2];
    const float* ew0  = (const float*)d_in[5];
    const float* eb0  = (const float*)d_in[6];
    const float* ew1  = (const float*)d_in[7];
    const float* eb1  = (const float*)d_in[8];
    const float* elng = (const float*)d_in[9];
    const float* elnb = (const float*)d_in[10];
    const float* nw0  = (const float*)d_in[11];
    const float* nb0  = (const float*)d_in[12];
    const float* nw1  = (const float*)d_in[13];
    const float* nb1  = (const float*)d_in[14];
    const float* nlng = (const float*)d_in[15];
    const float* nlnb = (const float*)d_in[16];
    const int* srcI = eidx;
    const int* tgtI = eidx + N_EDGES;

    // ---- workspace layout (bytes) ----
    char* ws = (char*)d_ws;
    size_t o = 0;
    short* ea_bf  = (short*)(ws + o); o += (size_t)N_EDGES * 128 * 2;       // 153.6 MB (permuted)
    short* Pb     = (short*)(ws + o); o += (size_t)N_NODES * 128 * 2;       // 25.6 MB
    short* Qb     = (short*)(ws + o); o += (size_t)N_NODES * 128 * 2;       // 25.6 MB
    short* aggb   = (short*)(ws + o); o += (size_t)N_NODES * 128 * 2;       // 25.6 MB
    short* xbA    = (short*)(ws + o); o += (size_t)N_NODES * 128 * 2;       // 25.6 MB
    short* xbB    = (short*)(ws + o); o += (size_t)N_NODES * 128 * 2;       // 25.6 MB
    short* wpack  = (short*)(ws + o); o += (size_t)NMP * 114688 * 2;        // 0.92 MB
    int*   deg    = (int*)(ws + o);   o += (size_t)N_NODES * 4;
    int*   offA   = (int*)(ws + o);   o += (size_t)(N_NODES + 1) * 4;
    int*   cursor = (int*)(ws + o);   o += (size_t)N_NODES * 4;
    int*   bsum   = (int*)(ws + o);   o += (size_t)NB_SCAN * 4;
    int*   bbase  = (int*)(ws + o);   o += (size_t)NB_SCAN * 4;
    int*   elist  = (int*)(ws + o);   o += (size_t)N_EDGES * 4;
    int*   psrc   = (int*)(ws + o);   o += (size_t)N_EDGES * 4;
    int*   ptgt   = (int*)(ws + o);   o += (size_t)N_EDGES * 4;
    float* xbuf   = (float*)d_out;

    // ---- one-time: weight pack + CSR + permuted index arrays ----
    pack_weights<<<(NMP * 14336 + 255) / 256, 256, 0, stream>>>(ew0, ew1, nw0, nw1, wpack);
    hipMemsetAsync(deg, 0, (size_t)N_NODES * 4, stream);
    deg_count<<<(N_EDGES + 255) / 256, 256, 0, stream>>>(tgtI, deg);
    scan_reduce<<<NB_SCAN, 256, 0, stream>>>(deg, bsum);
    scan_top<<<1, 64, 0, stream>>>(bsum, bbase, offA);
    scan_apply<<<NB_SCAN, 256, 0, stream>>>(deg, bbase, offA, cursor);
    fill_csr<<<(N_EDGES + 255) / 256, 256, 0, stream>>>(tgtI, cursor, elist);
    build_perm<<<(N_EDGES + 255) / 256, 256, 0, stream>>>(srcI, tgtI, elist, psrc, ptgt);

    const int ngrid = (N_NODES + 63) / 64;
    const int egrid = (N_EDGES + 127) / 128;
    // iter-0 P/Q from input x
    xform_kernel<<<ngrid, 256, 0, stream>>>(x_in, Pb, Qb, wpack);

    // bf16 x ping-pong: iter0 writes xbA; iter1 xbA->xbB; iter2 xbB->xbA;
    // iter3 reads xbA, writes f32 d_out.
    short* xbin[4]  = {nullptr, xbA, xbB, xbA};
    short* xbout[4] = {xbA, xbB, xbA, nullptr};

    for (int i = 0; i < NMP; i++) {
        const short* wp = wpack + (size_t)i * 114688;
        const short* wnext = wpack + (size_t)(i + 1) * 114688;   // unused when i==3
        if (i == 0) {
            edge_kernel<true><<<egrid, 512, 0, stream>>>(
                Pb, Qb, (const void*)ea_in0, ea_bf, psrc, ptgt, elist,
                wp + 0,
                eb0 + i * 128, eb1 + i * 128, elng + i * 128, elnb + i * 128);
        } else {
            edge_kernel<false><<<egrid, 512, 0, stream>>>(
                Pb, Qb, (const void*)ea_bf, ea_bf, psrc, ptgt, elist,
                wp + 0,
                eb0 + i * 128, eb1 + i * 128, elng + i * 128, elnb + i * 128);
        }
        agg_kernel<<<(N_NODES * 64 + 255) / 256, 256, 0, stream>>>(ea_bf, offA, aggb);
        if (i == 0) {
            node_kernel<true, false, true><<<ngrid, 256, 0, stream>>>(
                x_in, nullptr, nullptr, xbout[i], aggb,
                wp + 65536, wp + 98304, wnext, Pb, Qb,
                nb0 + i * 128, nb1 + i * 128, nlng + i * 128, nlnb + i * 128);
        } else if (i < NMP - 1) {
            node_kernel<false, false, true><<<ngrid, 256, 0, stream>>>(
                nullptr, xbin[i], nullptr, xbout[i], aggb,
                wp + 65536, wp + 98304, wnext, Pb, Qb,
                nb0 + i * 128, nb1 + i * 128, nlng + i * 128, nlnb + i * 128);
        } else {
            node_kernel<false, true, false><<<ngrid, 256, 0, stream>>>(
                nullptr, xbin[i], xbuf, nullptr, aggb,
                wp + 65536, wp + 98304, wnext, Pb, Qb,
                nb0 + i * 128, nb1 + i * 128, nlng + i * 128, nlnb + i * 128);
        }
    }
}

// Round 15
// 1238.668 us; speedup vs baseline: 1.1891x; 1.0227x over previous
//
#include <hip/hip_runtime.h>
#include <hip/hip_bf16.h>

#define N_NODES 100000
#define N_EDGES 600000
#define NMP     4
#define NB_SCAN 391   // ceil(N_NODES/256)

typedef __attribute__((ext_vector_type(8))) short bf16x8;
typedef __attribute__((ext_vector_type(4))) float f32x4;

#define LGKM0() asm volatile("s_waitcnt lgkmcnt(0)" ::: "memory")

// Hardware RNE convert: plain cast lets the compiler emit v_cvt_pk_bf16_f32
// (1 op / 2 elems) instead of ~4-5 VALU ops of manual bit-rounding.
__device__ __forceinline__ short f2bf(float f) {
    union { __hip_bfloat16 h; short s; } u;
    u.h = __float2bfloat16(f);
    return u.s;
}
__device__ __forceinline__ float bf2f(short s) {
    return __uint_as_float(((unsigned int)(unsigned short)s) << 16);
}

// ---------------------------------------------------------------------------
// Pack weights [K][128] f32 -> MFMA B-fragment order bf16:
// frag(kt,nt,lane)[j] = W[kt*32 + (lane>>4)*8 + j][nt*16 + (lane&15)]
// Per-iter packed layout (elems): edge_w0 @0 (49152), edge_w1 @49152 (16384),
// node_w0 @65536 (32768), node_w1 @98304 (16384); iter stride 114688.
// W0c (ea part, kt 8..11) = elems [32768,49152); W1 = [49152,65536).
// ---------------------------------------------------------------------------
__global__ void pack_weights(const float* __restrict__ ew0, const float* __restrict__ ew1,
                             const float* __restrict__ nw0, const float* __restrict__ nw1,
                             short* __restrict__ out) {
    int t = blockIdx.x * blockDim.x + threadIdx.x;
    if (t >= NMP * 14336) return;
    int it = t / 14336;
    int r  = t % 14336;
    const float* W; int obase;
    if (r < 6144)       { W = ew0 + (size_t)it*384*128; obase = 0;     }
    else if (r < 8192)  { W = ew1 + (size_t)it*128*128; obase = 49152; r -= 6144;  }
    else if (r < 12288) { W = nw0 + (size_t)it*256*128; obase = 65536; r -= 8192;  }
    else                { W = nw1 + (size_t)it*128*128; obase = 98304; r -= 12288; }
    int kt   = r >> 9;
    int rem  = r & 511;
    int nt   = rem >> 6;
    int lane = rem & 63;
    short* o = out + (size_t)it*114688 + obase + ((size_t)(kt*8 + nt)*64 + lane)*8;
    int kbase = kt*32 + (lane >> 4)*8;
    int n     = nt*16 + (lane & 15);
    #pragma unroll
    for (int j = 0; j < 8; j++) o[j] = f2bf(W[(size_t)(kbase + j)*128 + n]);
}

// ------------------------- CSR build (once per launch) ----------------------
__global__ void deg_count(const int* __restrict__ tgt, int* __restrict__ deg) {
    int e = blockIdx.x * blockDim.x + threadIdx.x;
    if (e < N_EDGES) atomicAdd(&deg[tgt[e]], 1);
}

__global__ void scan_reduce(const int* __restrict__ deg, int* __restrict__ bsum) {
    __shared__ int sh[256];
    int i = blockIdx.x * 256 + threadIdx.x;
    sh[threadIdx.x] = (i < N_NODES) ? deg[i] : 0;
    __syncthreads();
    for (int d = 128; d > 0; d >>= 1) {
        if (threadIdx.x < d) sh[threadIdx.x] += sh[threadIdx.x + d];
        __syncthreads();
    }
    if (threadIdx.x == 0) bsum[blockIdx.x] = sh[0];
}

__global__ void scan_top(const int* __restrict__ bsum, int* __restrict__ bbase,
                         int* __restrict__ off) {
    if (threadIdx.x == 0 && blockIdx.x == 0) {
        int run = 0;
        for (int b = 0; b < NB_SCAN; b++) { bbase[b] = run; run += bsum[b]; }
        off[N_NODES] = run;
    }
}

__global__ void scan_apply(const int* __restrict__ deg, const int* __restrict__ bbase,
                           int* __restrict__ off, int* __restrict__ cursor) {
    __shared__ int sh[256];
    int i = blockIdx.x * 256 + threadIdx.x;
    int v = (i < N_NODES) ? deg[i] : 0;
    sh[threadIdx.x] = v;
    __syncthreads();
    int acc = v;
    for (int d = 1; d < 256; d <<= 1) {
        int t = (threadIdx.x >= d) ? sh[threadIdx.x - d] : 0;
        __syncthreads();
        acc += t;
        sh[threadIdx.x] = acc;
        __syncthreads();
    }
    if (i < N_NODES) {
        int o = bbase[blockIdx.x] + acc - v;   // exclusive
        off[i] = o;
        cursor[i] = o;
    }
}

__global__ void fill_csr(const int* __restrict__ tgt, int* __restrict__ cursor,
                         int* __restrict__ elist) {
    int e = blockIdx.x * blockDim.x + threadIdx.x;
    if (e < N_EDGES) {
        int p = atomicAdd(&cursor[tgt[e]], 1);
        elist[p] = e;
    }
}

// psrc/ptgt: src/tgt per SORTED edge position
__global__ void build_perm(const int* __restrict__ srcI, const int* __restrict__ tgtI,
                           const int* __restrict__ elist,
                           int* __restrict__ psrc, int* __restrict__ ptgt) {
    int k = blockIdx.x * blockDim.x + threadIdx.x;
    if (k < N_EDGES) {
        int e = elist[k];
        psrc[k] = srcI[e];
        ptgt[k] = tgtI[e];
    }
}

// ---------------------------------------------------------------------------
// xform: P = x@W0a, Q = x@W0b  (bf16 outputs, [N][128] each) — iter 0 only.
// ---------------------------------------------------------------------------
__global__ __launch_bounds__(256)
void xform_kernel(const float* __restrict__ x_in,
                  short* __restrict__ P, short* __restrict__ Q,
                  const short* __restrict__ w0p) {
    const int tid  = threadIdx.x;
    const int wave = tid >> 6, lane = tid & 63;
    const int l15  = lane & 15, lg = lane >> 4;
    const long long nbase = (long long)blockIdx.x * 64 + wave * 16;
    long long arow = nbase + l15;
    if (arow >= N_NODES) arow = N_NODES - 1;

    f32x4 accP[8] = {}, accQ[8] = {};
    const bf16x8* w0f = (const bf16x8*)w0p;
    #pragma unroll
    for (int kt = 0; kt < 4; kt++) {
        const float* ap = x_in + arow*128 + kt*32 + lg*8;
        float4 f0 = *(const float4*)ap;
        float4 f1 = *(const float4*)(ap + 4);
        bf16x8 af;
        af[0]=f2bf(f0.x); af[1]=f2bf(f0.y); af[2]=f2bf(f0.z); af[3]=f2bf(f0.w);
        af[4]=f2bf(f1.x); af[5]=f2bf(f1.y); af[6]=f2bf(f1.z); af[7]=f2bf(f1.w);
        #pragma unroll
        for (int nt = 0; nt < 8; nt++) {
            accP[nt] = __builtin_amdgcn_mfma_f32_16x16x32_bf16(af, w0f[(size_t)(kt*8 + nt)*64 + lane], accP[nt], 0, 0, 0);
            accQ[nt] = __builtin_amdgcn_mfma_f32_16x16x32_bf16(af, w0f[(size_t)((kt+4)*8 + nt)*64 + lane], accQ[nt], 0, 0, 0);
        }
    }
    #pragma unroll
    for (int nt = 0; nt < 8; nt++) {
        int col = nt*16 + l15;
        #pragma unroll
        for (int j = 0; j < 4; j++) {
            long long r = nbase + lg*4 + j;
            if (r < N_NODES) {
                P[r*128 + col] = f2bf(accP[nt][j]);
                Q[r*128 + col] = f2bf(accQ[nt][j]);
            }
        }
    }
}

// ---------------------------------------------------------------------------
// Edge kernel — r9 structure (best measured: 192 us):
// 512 threads (8 waves), 128 edges/block, CSR-sorted edges.
// LDS 67.8KB -> 2 blocks/CU: W1 staged in LDS (32KB), W0c B-frags from
// global/L2. Wide dwordx4 epilogue stores via per-wave pq tile staging.
// ---------------------------------------------------------------------------
template<bool EAF32>
__global__ __launch_bounds__(512)
void edge_kernel(const short* __restrict__ P,
                 const short* __restrict__ Q,
                 const void* __restrict__ ea_in_v,
                 short* __restrict__ ea_out,
                 const int* __restrict__ psrc,
                 const int* __restrict__ ptgt,
                 const int* __restrict__ elist,
                 const short* __restrict__ w0p,
                 const float* __restrict__ b0,
                 const float* __restrict__ b1,
                 const float* __restrict__ lng,
                 const float* __restrict__ lnb) {
    __shared__ __align__(16) short w1lds[16384];     // 32KB: W1
    __shared__ __align__(16) short pq[8][16][140];   // 35840B per-wave tiles
    const int tid  = threadIdx.x;
    const int wave = tid >> 6, lane = tid & 63;
    const int l15  = lane & 15, lg = lane >> 4;
    const long long ebase = (long long)blockIdx.x * 128 + wave * 16;
    const long long arow  = ebase + l15;
    const long long arc   = arow < N_EDGES ? arow : (N_EDGES - 1);
    const float* eaf = (const float*)ea_in_v;
    const short* eab = (const short*)ea_in_v;
    const bf16x8* w0c = (const bf16x8*)(w0p + 32768);   // W0c frags via L1/L2

    // --- issue W1 loads (32KB contiguous at w0p+49152) ---
    const short* w1src = w0p + 49152;
    bf16x8 wtmp[4];
    #pragma unroll
    for (int it = 0; it < 4; it++)
        wtmp[it] = *(const bf16x8*)(w1src + it*4096 + tid*8);

    // --- per-wave gather: P[psrc]+Q[ptgt] summed in registers ---
    {
        const int c8 = (lane & 7) * 16;        // 32B column chunk (shorts)
        #pragma unroll
        for (int pass = 0; pass < 2; pass++) {
            int rr = (lane >> 3) + pass * 8;
            long long e = ebase + rr;
            if (e >= N_EDGES) e = N_EDGES - 1;
            long long s = psrc[e], t = ptgt[e];
            bf16x8 p0 = *(const bf16x8*)(P + s*128 + c8);
            bf16x8 p1 = *(const bf16x8*)(P + s*128 + c8 + 8);
            bf16x8 q0 = *(const bf16x8*)(Q + t*128 + c8);
            bf16x8 q1 = *(const bf16x8*)(Q + t*128 + c8 + 8);
            bf16x8 u0, u1;
            #pragma unroll
            for (int k = 0; k < 8; k++) {
                u0[k] = f2bf(bf2f(p0[k]) + bf2f(q0[k]));
                u1[k] = f2bf(bf2f(p1[k]) + bf2f(q1[k]));
            }
            *(bf16x8*)&pq[wave][rr][c8]     = u0;
            *(bf16x8*)&pq[wave][rr][c8 + 8] = u1;
        }
    }

    // --- load ea fragments (A-operand + residual) ---
    bf16x8 eafrag[4];
    #pragma unroll
    for (int kt = 0; kt < 4; kt++) {
        if (EAF32) {
            long long orig = elist[arc];          // one-time scatter at iter 0
            const float* ap = eaf + orig*128 + kt*32 + lg*8;
            float4 f0 = *(const float4*)ap;
            float4 f1 = *(const float4*)(ap + 4);
            bf16x8 af;
            af[0]=f2bf(f0.x); af[1]=f2bf(f0.y); af[2]=f2bf(f0.z); af[3]=f2bf(f0.w);
            af[4]=f2bf(f1.x); af[5]=f2bf(f1.y); af[6]=f2bf(f1.z); af[7]=f2bf(f1.w);
            eafrag[kt] = af;
        } else {
            eafrag[kt] = *(const bf16x8*)(eab + arc*128 + kt*32 + lg*8);
        }
    }

    // --- commit W1 to LDS, block barrier (the only one) ---
    #pragma unroll
    for (int it = 0; it < 4; it++)
        *(bf16x8*)&w1lds[it*4096 + tid*8] = wtmp[it];
    __syncthreads();

    // --- layer0: ea @ W0c (B-frags from global/L1) ---
    f32x4 acc[8] = {};
    #pragma unroll
    for (int kt = 0; kt < 4; kt++) {
        #pragma unroll
        for (int nt = 0; nt < 8; nt++) {
            bf16x8 bfr = w0c[(size_t)(kt*8 + nt)*64 + lane];
            acc[nt] = __builtin_amdgcn_mfma_f32_16x16x32_bf16(eafrag[kt], bfr, acc[nt], 0, 0, 0);
        }
    }

    // --- bias + PQ add + ELU; hidden in place (lane-owned) ---
    #pragma unroll
    for (int nt = 0; nt < 8; nt++) {
        int col = nt*16 + l15;
        float bb = b0[col];
        #pragma unroll
        for (int j = 0; j < 4; j++) {
            int r = lg*4 + j;
            float v = acc[nt][j] + bb + bf2f(pq[wave][r][col]);
            v = v > 0.f ? v : (__expf(v) - 1.f);
            pq[wave][r][col] = f2bf(v);
        }
    }
    LGKM0();   // hidden visible to all lanes of this wave

    // --- layer1: hid @ W1 (B-frags from LDS) ---
    f32x4 acc2[8] = {};
    #pragma unroll
    for (int kt = 0; kt < 4; kt++) {
        bf16x8 af = *(const bf16x8*)&pq[wave][l15][kt*32 + lg*8];
        #pragma unroll
        for (int nt = 0; nt < 8; nt++) {
            bf16x8 bfr = *(const bf16x8*)&w1lds[((kt*8 + nt)*64 + lane)*8];
            acc2[nt] = __builtin_amdgcn_mfma_f32_16x16x32_bf16(af, bfr, acc2[nt], 0, 0, 0);
        }
    }
    LGKM0();   // hidden ds_reads drained -> tile reusable

    // --- stage ea fragments (residual source) ---
    #pragma unroll
    for (int kt = 0; kt < 4; kt++)
        *(bf16x8*)&pq[wave][l15][kt*32 + lg*8] = eafrag[kt];
    LGKM0();

    // --- residual (LDS) + LayerNorm ---
    float t[8][4];
    #pragma unroll
    for (int nt = 0; nt < 8; nt++) {
        int col = nt*16 + l15;
        float bb = b1[col];
        #pragma unroll
        for (int j = 0; j < 4; j++) {
            int r = lg*4 + j;
            t[nt][j] = acc2[nt][j] + bb + bf2f(pq[wave][r][col]);
        }
    }
    LGKM0();   // all residual reads done -> tile reusable for output staging

    #pragma unroll
    for (int j = 0; j < 4; j++) {
        float s = 0.f;
        #pragma unroll
        for (int nt = 0; nt < 8; nt++) s += t[nt][j];
        #pragma unroll
        for (int m = 1; m < 16; m <<= 1) s += __shfl_xor(s, m);
        float mean = s * (1.0f / 128.0f);
        float s2 = 0.f;
        #pragma unroll
        for (int nt = 0; nt < 8; nt++) { float d = t[nt][j] - mean; s2 += d*d; }
        #pragma unroll
        for (int m = 1; m < 16; m <<= 1) s2 += __shfl_xor(s2, m);
        float rstd = rsqrtf(s2 * (1.0f / 128.0f) + 1e-5f);
        int r = lg*4 + j;
        #pragma unroll
        for (int nt = 0; nt < 8; nt++) {
            int col = nt*16 + l15;
            pq[wave][r][col] = f2bf((t[nt][j] - mean) * rstd * lng[col] + lnb[col]);
        }
    }
    LGKM0();   // LN output staged (wave-local)

    // --- wide coalesced store: wave streams its 16 rows (4KB) ---
    #pragma unroll
    for (int k = 0; k < 4; k++) {
        int row = k*4 + (lane >> 4);
        long long erow = ebase + row;
        bf16x8 vv = *(const bf16x8*)&pq[wave][row][l15*8];
        if (erow < N_EDGES)
            *(bf16x8*)&ea_out[erow*128 + l15*8] = vv;
    }
}

// ---------------------------------------------------------------------------
// Aggregation: one wave per node; ea rows for node n are CONTIGUOUS
// [off[n], off[n+1]) in the permuted layout -> pure streaming read.
// ---------------------------------------------------------------------------
__global__ __launch_bounds__(256)
void agg_kernel(const short* __restrict__ ea,
                const int* __restrict__ off,
                short* __restrict__ aggb) {
    const int wid  = (blockIdx.x * 256 + threadIdx.x) >> 6;
    const int lane = threadIdx.x & 63;
    if (wid >= N_NODES) return;
    const int o0 = off[wid], o1 = off[wid + 1];
    float s0 = 0.f, s1 = 0.f;
    for (int i = o0; i < o1; i++) {
        unsigned int v = *(const unsigned int*)(ea + (long long)i*128 + lane*2);
        s0 += __uint_as_float(v << 16);
        s1 += __uint_as_float(v & 0xFFFF0000u);
    }
    float inv = (o1 > o0) ? 1.f / (float)(o1 - o0) : 0.f;
    short2 w;
    w.x = f2bf(s0 * inv);
    w.y = f2bf(s1 * inv);
    *(short2*)(aggb + (long long)wid*128 + lane*2) = w;
}

// ---------------------------------------------------------------------------
// Node kernel + fused P/Q production. x kept bf16 between iterations:
//   XF32IN : read x from f32 (iter 0) vs bf16 ping-pong buffer
//   XF32OUT: write f32 x to d_out (last iter) vs wide bf16 store
//   MAKEPQ : produce next-iter P/Q from LN'd x staged in hid tile
// ---------------------------------------------------------------------------
template<bool XF32IN, bool XF32OUT, bool MAKEPQ>
__global__ __launch_bounds__(256)
void node_kernel(const float* __restrict__ xf_in,
                 const short* __restrict__ xb_in,
                 float* __restrict__ xf_out,
                 short* __restrict__ xb_out,
                 const short* __restrict__ aggb,
                 const short* __restrict__ w0p,
                 const short* __restrict__ w1p,
                 const short* __restrict__ wnext,
                 short* __restrict__ P,
                 short* __restrict__ Q,
                 const float* __restrict__ b0,
                 const float* __restrict__ b1,
                 const float* __restrict__ lng,
                 const float* __restrict__ lnb) {
    __shared__ __align__(16) short hid[4][16][140];
    const int tid  = threadIdx.x;
    const int wave = tid >> 6, lane = tid & 63;
    const int l15  = lane & 15, lg = lane >> 4;
    const long long nbase = (long long)blockIdx.x * 64 + wave * 16;
    long long arow = nbase + l15;
    if (arow >= N_NODES) arow = N_NODES - 1;

    f32x4 acc[8] = {};
    const bf16x8* w0f = (const bf16x8*)w0p;
    #pragma unroll
    for (int kt = 0; kt < 8; kt++) {
        int k0 = kt*32 + lg*8;
        bf16x8 af;
        if (k0 < 128) {
            if (XF32IN) {
                const float* ap = xf_in + arow*128 + k0;
                float4 f0 = *(const float4*)ap;
                float4 f1 = *(const float4*)(ap + 4);
                af[0]=f2bf(f0.x); af[1]=f2bf(f0.y); af[2]=f2bf(f0.z); af[3]=f2bf(f0.w);
                af[4]=f2bf(f1.x); af[5]=f2bf(f1.y); af[6]=f2bf(f1.z); af[7]=f2bf(f1.w);
            } else {
                af = *(const bf16x8*)(xb_in + arow*128 + k0);
            }
        } else {
            af = *(const bf16x8*)(aggb + arow*128 + (k0 - 128));
        }
        #pragma unroll
        for (int nt = 0; nt < 8; nt++) {
            bf16x8 bfr = w0f[(size_t)(kt*8 + nt)*64 + lane];
            acc[nt] = __builtin_amdgcn_mfma_f32_16x16x32_bf16(af, bfr, acc[nt], 0, 0, 0);
        }
    }
    #pragma unroll
    for (int nt = 0; nt < 8; nt++) {
        int col = nt*16 + l15;
        float bb = b0[col];
        #pragma unroll
        for (int j = 0; j < 4; j++) {
            float v = acc[nt][j] + bb;
            v = v > 0.f ? v : (__expf(v) - 1.f);
            hid[wave][lg*4 + j][col] = f2bf(v);
        }
    }
    LGKM0();   // hid writes complete (wave-local)

    f32x4 acc2[8] = {};
    const bf16x8* w1f = (const bf16x8*)w1p;
    #pragma unroll
    for (int kt = 0; kt < 4; kt++) {
        bf16x8 af = *(const bf16x8*)&hid[wave][l15][kt*32 + lg*8];
        #pragma unroll
        for (int nt = 0; nt < 8; nt++) {
            bf16x8 bfr = w1f[(size_t)(kt*8 + nt)*64 + lane];
            acc2[nt] = __builtin_amdgcn_mfma_f32_16x16x32_bf16(af, bfr, acc2[nt], 0, 0, 0);
        }
    }
    float t[8][4];
    #pragma unroll
    for (int nt = 0; nt < 8; nt++) {
        int col = nt*16 + l15;
        float bb = b1[col];
        #pragma unroll
        for (int j = 0; j < 4; j++) {
            long long nrow = nbase + lg*4 + j;
            long long nrc  = nrow < N_NODES ? nrow : (N_NODES - 1);
            float res = XF32IN ? xf_in[nrc*128 + col] : bf2f(xb_in[nrc*128 + col]);
            t[nt][j] = acc2[nt][j] + bb + res;
        }
    }
    float xo[8][4];
    #pragma unroll
    for (int j = 0; j < 4; j++) {
        float s = 0.f;
        #pragma unroll
        for (int nt = 0; nt < 8; nt++) s += t[nt][j];
        #pragma unroll
        for (int m = 1; m < 16; m <<= 1) s += __shfl_xor(s, m);
        float mean = s * (1.0f / 128.0f);
        float s2 = 0.f;
        #pragma unroll
        for (int nt = 0; nt < 8; nt++) { float d = t[nt][j] - mean; s2 += d*d; }
        #pragma unroll
        for (int m = 1; m < 16; m <<= 1) s2 += __shfl_xor(s2, m);
        float rstd = rsqrtf(s2 * (1.0f / 128.0f) + 1e-5f);
        long long nrow = nbase + lg*4 + j;
        #pragma unroll
        for (int nt = 0; nt < 8; nt++) {
            int col = nt*16 + l15;
            float v = (t[nt][j] - mean) * rstd * lng[col] + lnb[col];
            xo[nt][j] = v;
            if (XF32OUT && nrow < N_NODES) xf_out[nrow*128 + col] = v;
        }
    }

    if (!XF32OUT || MAKEPQ) {
        // stage LN'd x (bf16) into drained hid tile
        LGKM0();   // layer1 ds_reads drained
        #pragma unroll
        for (int nt = 0; nt < 8; nt++) {
            int col = nt*16 + l15;
            #pragma unroll
            for (int j = 0; j < 4; j++)
                hid[wave][lg*4 + j][col] = f2bf(xo[nt][j]);
        }
        LGKM0();
    }

    if (!XF32OUT) {
        // wide coalesced bf16 x store: wave streams its 16 rows (4KB)
        #pragma unroll
        for (int k = 0; k < 4; k++) {
            int row = k*4 + (lane >> 4);
            long long nrow = nbase + row;
            bf16x8 vv = *(const bf16x8*)&hid[wave][row][l15*8];
            if (nrow < N_NODES)
                *(bf16x8*)&xb_out[nrow*128 + l15*8] = vv;
        }
    }

    if (MAKEPQ) {
        const bf16x8* wn = (const bf16x8*)wnext;
        {
            f32x4 accP[8] = {};
            #pragma unroll
            for (int kt = 0; kt < 4; kt++) {
                bf16x8 af = *(const bf16x8*)&hid[wave][l15][kt*32 + lg*8];
                #pragma unroll
                for (int nt = 0; nt < 8; nt++)
                    accP[nt] = __builtin_amdgcn_mfma_f32_16x16x32_bf16(af, wn[(size_t)(kt*8 + nt)*64 + lane], accP[nt], 0, 0, 0);
            }
            #pragma unroll
            for (int nt = 0; nt < 8; nt++) {
                int col = nt*16 + l15;
                #pragma unroll
                for (int j = 0; j < 4; j++) {
                    long long r = nbase + lg*4 + j;
                    if (r < N_NODES) P[r*128 + col] = f2bf(accP[nt][j]);
                }
            }
        }
        {
            f32x4 accQ[8] = {};
            #pragma unroll
            for (int kt = 0; kt < 4; kt++) {
                bf16x8 af = *(const bf16x8*)&hid[wave][l15][kt*32 + lg*8];
                #pragma unroll
                for (int nt = 0; nt < 8; nt++)
                    accQ[nt] = __builtin_amdgcn_mfma_f32_16x16x32_bf16(af, wn[(size_t)((kt+4)*8 + nt)*64 + lane], accQ[nt], 0, 0, 0);
            }
            #pragma unroll
            for (int nt = 0; nt < 8; nt++) {
                int col = nt*16 + l15;
                #pragma unroll
                for (int j = 0; j < 4; j++) {
                    long long r = nbase + lg*4 + j;
                    if (r < N_NODES) Q[r*128 + col] = f2bf(accQ[nt][j]);
                }
            }
        }
    }
}

extern "C" void kernel_launch(void* const* d_in, const int* in_sizes, int n_in,
                              void* d_out, int out_size, void* d_ws, size_t ws_size,
                              hipStream_t stream) {
    const float* x_in   = (const float*)d_in[0];
    const int*   eidx   = (const int*)d_in[1];
    const float* ea_in0 = (const float*)d_in[2];
    const float* ew0  = (const float*)d_in[5];
    const float* eb0  = (const float*)d_in[6];
    const float* ew1  = (const float*)d_in[7];
    const float* eb1  = (const float*)d_in[8];
    const float* elng = (const float*)d_in[9];
    const float* elnb = (const float*)d_in[10];
    const float* nw0  = (const float*)d_in[11];
    const float* nb0  = (const float*)d_in[12];
    const float* nw1  = (const float*)d_in[13];
    const float* nb1  = (const float*)d_in[14];
    const float* nlng = (const float*)d_in[15];
    const float* nlnb = (const float*)d_in[16];
    const int* srcI = eidx;
    const int* tgtI = eidx + N_EDGES;

    // ---- workspace layout (bytes) ----
    char* ws = (char*)d_ws;
    size_t o = 0;
    short* ea_bf  = (short*)(ws + o); o += (size_t)N_EDGES * 128 * 2;       // 153.6 MB (permuted)
    short* Pb     = (short*)(ws + o); o += (size_t)N_NODES * 128 * 2;       // 25.6 MB
    short* Qb     = (short*)(ws + o); o += (size_t)N_NODES * 128 * 2;       // 25.6 MB
    short* aggb   = (short*)(ws + o); o += (size_t)N_NODES * 128 * 2;       // 25.6 MB
    short* xbA    = (short*)(ws + o); o += (size_t)N_NODES * 128 * 2;       // 25.6 MB
    short* xbB    = (short*)(ws + o); o += (size_t)N_NODES * 128 * 2;       // 25.6 MB
    short* wpack  = (short*)(ws + o); o += (size_t)NMP * 114688 * 2;        // 0.92 MB
    int*   deg    = (int*)(ws + o);   o += (size_t)N_NODES * 4;
    int*   offA   = (int*)(ws + o);   o += (size_t)(N_NODES + 1) * 4;
    int*   cursor = (int*)(ws + o);   o += (size_t)N_NODES * 4;
    int*   bsum   = (int*)(ws + o);   o += (size_t)NB_SCAN * 4;
    int*   bbase  = (int*)(ws + o);   o += (size_t)NB_SCAN * 4;
    int*   elist  = (int*)(ws + o);   o += (size_t)N_EDGES * 4;
    int*   psrc   = (int*)(ws + o);   o += (size_t)N_EDGES * 4;
    int*   ptgt   = (int*)(ws + o);   o += (size_t)N_EDGES * 4;
    float* xbuf   = (float*)d_out;

    // ---- one-time: weight pack + CSR + permuted index arrays ----
    pack_weights<<<(NMP * 14336 + 255) / 256, 256, 0, stream>>>(ew0, ew1, nw0, nw1, wpack);
    hipMemsetAsync(deg, 0, (size_t)N_NODES * 4, stream);
    deg_count<<<(N_EDGES + 255) / 256, 256, 0, stream>>>(tgtI, deg);
    scan_reduce<<<NB_SCAN, 256, 0, stream>>>(deg, bsum);
    scan_top<<<1, 64, 0, stream>>>(bsum, bbase, offA);
    scan_apply<<<NB_SCAN, 256, 0, stream>>>(deg, bbase, offA, cursor);
    fill_csr<<<(N_EDGES + 255) / 256, 256, 0, stream>>>(tgtI, cursor, elist);
    build_perm<<<(N_EDGES + 255) / 256, 256, 0, stream>>>(srcI, tgtI, elist, psrc, ptgt);

    const int ngrid = (N_NODES + 63) / 64;
    const int egrid = (N_EDGES + 127) / 128;
    // iter-0 P/Q from input x
    xform_kernel<<<ngrid, 256, 0, stream>>>(x_in, Pb, Qb, wpack);

    // bf16 x ping-pong: iter0 writes xbA; iter1 xbA->xbB; iter2 xbB->xbA;
    // iter3 reads xbA, writes f32 d_out.
    short* xbin[4]  = {nullptr, xbA, xbB, xbA};
    short* xbout[4] = {xbA, xbB, xbA, nullptr};

    for (int i = 0; i < NMP; i++) {
        const short* wp = wpack + (size_t)i * 114688;
        const short* wnext = wpack + (size_t)(i + 1) * 114688;   // unused when i==3
        if (i == 0) {
            edge_kernel<true><<<egrid, 512, 0, stream>>>(
                Pb, Qb, (const void*)ea_in0, ea_bf, psrc, ptgt, elist,
                wp + 0,
                eb0 + i * 128, eb1 + i * 128, elng + i * 128, elnb + i * 128);
        } else {
            edge_kernel<false><<<egrid, 512, 0, stream>>>(
                Pb, Qb, (const void*)ea_bf, ea_bf, psrc, ptgt, elist,
                wp + 0,
                eb0 + i * 128, eb1 + i * 128, elng + i * 128, elnb + i * 128);
        }
        agg_kernel<<<(N_NODES * 64 + 255) / 256, 256, 0, stream>>>(ea_bf, offA, aggb);
        if (i == 0) {
            node_kernel<true, false, true><<<ngrid, 256, 0, stream>>>(
                x_in, nullptr, nullptr, xbout[i], aggb,
                wp + 65536, wp + 98304, wnext, Pb, Qb,
                nb0 + i * 128, nb1 + i * 128, nlng + i * 128, nlnb + i * 128);
        } else if (i < NMP - 1) {
            node_kernel<false, false, true><<<ngrid, 256, 0, stream>>>(
                nullptr, xbin[i], nullptr, xbout[i], aggb,
                wp + 65536, wp + 98304, wnext, Pb, Qb,
                nb0 + i * 128, nb1 + i * 128, nlng + i * 128, nlnb + i * 128);
        } else {
            node_kernel<false, true, false><<<ngrid, 256, 0, stream>>>(
                nullptr, xbin[i], xbuf, nullptr, aggb,
                wp + 65536, wp + 98304, wnext, Pb, Qb,
                nb0 + i * 128, nb1 + i * 128, nlng + i * 128, nlnb + i * 128);
        }
    }
}

// Round 16
// 1132.247 us; speedup vs baseline: 1.3009x; 1.0940x over previous
//
#include <hip/hip_runtime.h>
#include <hip/hip_bf16.h>

#define N_NODES 100000
#define N_EDGES 600000
#define NMP     4
#define NB_SCAN 391   // ceil(N_NODES/256)

typedef __attribute__((ext_vector_type(8))) short bf16x8;
typedef __attribute__((ext_vector_type(4))) float f32x4;

#define LGKM0() asm volatile("s_waitcnt lgkmcnt(0)" ::: "memory")

// Hardware RNE convert (compiler emits v_cvt_pk_bf16_f32).
__device__ __forceinline__ short f2bf(float f) {
    union { __hip_bfloat16 h; short s; } u;
    u.h = __float2bfloat16(f);
    return u.s;
}
__device__ __forceinline__ float bf2f(short s) {
    return __uint_as_float(((unsigned int)(unsigned short)s) << 16);
}

// ---------------------------------------------------------------------------
// Pack weights [K][128] f32 -> MFMA B-fragment order bf16:
// frag(kt,nt,lane)[j] = W[kt*32 + (lane>>4)*8 + j][nt*16 + (lane&15)]
// Per-iter packed layout (elems): edge_w0 @0 (49152), edge_w1 @49152 (16384),
// node_w0 @65536 (32768), node_w1 @98304 (16384); iter stride 114688.
// W0c (ea part, kt 8..11) = elems [32768,49152); W1 = [49152,65536).
// ---------------------------------------------------------------------------
__global__ void pack_weights(const float* __restrict__ ew0, const float* __restrict__ ew1,
                             const float* __restrict__ nw0, const float* __restrict__ nw1,
                             short* __restrict__ out) {
    int t = blockIdx.x * blockDim.x + threadIdx.x;
    if (t >= NMP * 14336) return;
    int it = t / 14336;
    int r  = t % 14336;
    const float* W; int obase;
    if (r < 6144)       { W = ew0 + (size_t)it*384*128; obase = 0;     }
    else if (r < 8192)  { W = ew1 + (size_t)it*128*128; obase = 49152; r -= 6144;  }
    else if (r < 12288) { W = nw0 + (size_t)it*256*128; obase = 65536; r -= 8192;  }
    else                { W = nw1 + (size_t)it*128*128; obase = 98304; r -= 12288; }
    int kt   = r >> 9;
    int rem  = r & 511;
    int nt   = rem >> 6;
    int lane = rem & 63;
    short* o = out + (size_t)it*114688 + obase + ((size_t)(kt*8 + nt)*64 + lane)*8;
    int kbase = kt*32 + (lane >> 4)*8;
    int n     = nt*16 + (lane & 15);
    #pragma unroll
    for (int j = 0; j < 8; j++) o[j] = f2bf(W[(size_t)(kbase + j)*128 + n]);
}

// ------------------------- CSR build (once per launch) ----------------------
__global__ void deg_count(const int* __restrict__ tgt, int* __restrict__ deg) {
    int e = blockIdx.x * blockDim.x + threadIdx.x;
    if (e < N_EDGES) atomicAdd(&deg[tgt[e]], 1);
}

__global__ void scan_reduce(const int* __restrict__ deg, int* __restrict__ bsum) {
    __shared__ int sh[256];
    int i = blockIdx.x * 256 + threadIdx.x;
    sh[threadIdx.x] = (i < N_NODES) ? deg[i] : 0;
    __syncthreads();
    for (int d = 128; d > 0; d >>= 1) {
        if (threadIdx.x < d) sh[threadIdx.x] += sh[threadIdx.x + d];
        __syncthreads();
    }
    if (threadIdx.x == 0) bsum[blockIdx.x] = sh[0];
}

__global__ void scan_top(const int* __restrict__ bsum, int* __restrict__ bbase,
                         int* __restrict__ off) {
    if (threadIdx.x == 0 && blockIdx.x == 0) {
        int run = 0;
        for (int b = 0; b < NB_SCAN; b++) { bbase[b] = run; run += bsum[b]; }
        off[N_NODES] = run;
    }
}

__global__ void scan_apply(const int* __restrict__ deg, const int* __restrict__ bbase,
                           int* __restrict__ off, int* __restrict__ cursor) {
    __shared__ int sh[256];
    int i = blockIdx.x * 256 + threadIdx.x;
    int v = (i < N_NODES) ? deg[i] : 0;
    sh[threadIdx.x] = v;
    __syncthreads();
    int acc = v;
    for (int d = 1; d < 256; d <<= 1) {
        int t = (threadIdx.x >= d) ? sh[threadIdx.x - d] : 0;
        __syncthreads();
        acc += t;
        sh[threadIdx.x] = acc;
        __syncthreads();
    }
    if (i < N_NODES) {
        int o = bbase[blockIdx.x] + acc - v;   // exclusive
        off[i] = o;
        cursor[i] = o;
    }
}

__global__ void fill_csr(const int* __restrict__ tgt, int* __restrict__ cursor,
                         int* __restrict__ elist) {
    int e = blockIdx.x * blockDim.x + threadIdx.x;
    if (e < N_EDGES) {
        int p = atomicAdd(&cursor[tgt[e]], 1);
        elist[p] = e;
    }
}

// psrc/ptgt: src/tgt per SORTED edge position
__global__ void build_perm(const int* __restrict__ srcI, const int* __restrict__ tgtI,
                           const int* __restrict__ elist,
                           int* __restrict__ psrc, int* __restrict__ ptgt) {
    int k = blockIdx.x * blockDim.x + threadIdx.x;
    if (k < N_EDGES) {
        int e = elist[k];
        psrc[k] = srcI[e];
        ptgt[k] = tgtI[e];
    }
}

// ---------------------------------------------------------------------------
// xform: P = x@W0a, Q = x@W0b  (bf16, wide-store via LDS staging) — iter 0.
// ---------------------------------------------------------------------------
__global__ __launch_bounds__(256)
void xform_kernel(const float* __restrict__ x_in,
                  short* __restrict__ P, short* __restrict__ Q,
                  const short* __restrict__ w0p) {
    __shared__ __align__(16) short outt[4][16][140];
    const int tid  = threadIdx.x;
    const int wave = tid >> 6, lane = tid & 63;
    const int l15  = lane & 15, lg = lane >> 4;
    const long long nbase = (long long)blockIdx.x * 64 + wave * 16;
    long long arow = nbase + l15;
    if (arow >= N_NODES) arow = N_NODES - 1;

    f32x4 accP[8] = {}, accQ[8] = {};
    const bf16x8* w0f = (const bf16x8*)w0p;
    #pragma unroll
    for (int kt = 0; kt < 4; kt++) {
        const float* ap = x_in + arow*128 + kt*32 + lg*8;
        float4 f0 = *(const float4*)ap;
        float4 f1 = *(const float4*)(ap + 4);
        bf16x8 af;
        af[0]=f2bf(f0.x); af[1]=f2bf(f0.y); af[2]=f2bf(f0.z); af[3]=f2bf(f0.w);
        af[4]=f2bf(f1.x); af[5]=f2bf(f1.y); af[6]=f2bf(f1.z); af[7]=f2bf(f1.w);
        #pragma unroll
        for (int nt = 0; nt < 8; nt++) {
            accP[nt] = __builtin_amdgcn_mfma_f32_16x16x32_bf16(af, w0f[(size_t)(kt*8 + nt)*64 + lane], accP[nt], 0, 0, 0);
            accQ[nt] = __builtin_amdgcn_mfma_f32_16x16x32_bf16(af, w0f[(size_t)((kt+4)*8 + nt)*64 + lane], accQ[nt], 0, 0, 0);
        }
    }
    // stage P -> wide store
    #pragma unroll
    for (int nt = 0; nt < 8; nt++) {
        int col = nt*16 + l15;
        #pragma unroll
        for (int j = 0; j < 4; j++)
            outt[wave][lg*4 + j][col] = f2bf(accP[nt][j]);
    }
    LGKM0();
    #pragma unroll
    for (int k = 0; k < 4; k++) {
        int row = k*4 + (lane >> 4);
        long long nrow = nbase + row;
        bf16x8 vv = *(const bf16x8*)&outt[wave][row][l15*8];
        if (nrow < N_NODES)
            *(bf16x8*)&P[nrow*128 + l15*8] = vv;
    }
    LGKM0();   // store-source reads done -> tile reusable
    // stage Q -> wide store
    #pragma unroll
    for (int nt = 0; nt < 8; nt++) {
        int col = nt*16 + l15;
        #pragma unroll
        for (int j = 0; j < 4; j++)
            outt[wave][lg*4 + j][col] = f2bf(accQ[nt][j]);
    }
    LGKM0();
    #pragma unroll
    for (int k = 0; k < 4; k++) {
        int row = k*4 + (lane >> 4);
        long long nrow = nbase + row;
        bf16x8 vv = *(const bf16x8*)&outt[wave][row][l15*8];
        if (nrow < N_NODES)
            *(bf16x8*)&Q[nrow*128 + l15*8] = vv;
    }
}

// ---------------------------------------------------------------------------
// Edge kernel — r9 structure (best measured: 190 us):
// 512 threads (8 waves), 128 edges/block, CSR-sorted edges.
// LDS 67.8KB -> 2 blocks/CU: W1 staged in LDS (32KB), W0c B-frags from
// global/L2. Wide dwordx4 epilogue stores via per-wave pq tile staging.
// ---------------------------------------------------------------------------
template<bool EAF32>
__global__ __launch_bounds__(512)
void edge_kernel(const short* __restrict__ P,
                 const short* __restrict__ Q,
                 const void* __restrict__ ea_in_v,
                 short* __restrict__ ea_out,
                 const int* __restrict__ psrc,
                 const int* __restrict__ ptgt,
                 const int* __restrict__ elist,
                 const short* __restrict__ w0p,
                 const float* __restrict__ b0,
                 const float* __restrict__ b1,
                 const float* __restrict__ lng,
                 const float* __restrict__ lnb) {
    __shared__ __align__(16) short w1lds[16384];     // 32KB: W1
    __shared__ __align__(16) short pq[8][16][140];   // 35840B per-wave tiles
    const int tid  = threadIdx.x;
    const int wave = tid >> 6, lane = tid & 63;
    const int l15  = lane & 15, lg = lane >> 4;
    const long long ebase = (long long)blockIdx.x * 128 + wave * 16;
    const long long arow  = ebase + l15;
    const long long arc   = arow < N_EDGES ? arow : (N_EDGES - 1);
    const float* eaf = (const float*)ea_in_v;
    const short* eab = (const short*)ea_in_v;
    const bf16x8* w0c = (const bf16x8*)(w0p + 32768);   // W0c frags via L1/L2

    // --- issue W1 loads (32KB contiguous at w0p+49152) ---
    const short* w1src = w0p + 49152;
    bf16x8 wtmp[4];
    #pragma unroll
    for (int it = 0; it < 4; it++)
        wtmp[it] = *(const bf16x8*)(w1src + it*4096 + tid*8);

    // --- per-wave gather: P[psrc]+Q[ptgt] summed in registers ---
    {
        const int c8 = (lane & 7) * 16;        // 32B column chunk (shorts)
        #pragma unroll
        for (int pass = 0; pass < 2; pass++) {
            int rr = (lane >> 3) + pass * 8;
            long long e = ebase + rr;
            if (e >= N_EDGES) e = N_EDGES - 1;
            long long s = psrc[e], t = ptgt[e];
            bf16x8 p0 = *(const bf16x8*)(P + s*128 + c8);
            bf16x8 p1 = *(const bf16x8*)(P + s*128 + c8 + 8);
            bf16x8 q0 = *(const bf16x8*)(Q + t*128 + c8);
            bf16x8 q1 = *(const bf16x8*)(Q + t*128 + c8 + 8);
            bf16x8 u0, u1;
            #pragma unroll
            for (int k = 0; k < 8; k++) {
                u0[k] = f2bf(bf2f(p0[k]) + bf2f(q0[k]));
                u1[k] = f2bf(bf2f(p1[k]) + bf2f(q1[k]));
            }
            *(bf16x8*)&pq[wave][rr][c8]     = u0;
            *(bf16x8*)&pq[wave][rr][c8 + 8] = u1;
        }
    }

    // --- load ea fragments (A-operand + residual) ---
    bf16x8 eafrag[4];
    #pragma unroll
    for (int kt = 0; kt < 4; kt++) {
        if (EAF32) {
            long long orig = elist[arc];          // one-time scatter at iter 0
            const float* ap = eaf + orig*128 + kt*32 + lg*8;
            float4 f0 = *(const float4*)ap;
            float4 f1 = *(const float4*)(ap + 4);
            bf16x8 af;
            af[0]=f2bf(f0.x); af[1]=f2bf(f0.y); af[2]=f2bf(f0.z); af[3]=f2bf(f0.w);
            af[4]=f2bf(f1.x); af[5]=f2bf(f1.y); af[6]=f2bf(f1.z); af[7]=f2bf(f1.w);
            eafrag[kt] = af;
        } else {
            eafrag[kt] = *(const bf16x8*)(eab + arc*128 + kt*32 + lg*8);
        }
    }

    // --- commit W1 to LDS, block barrier (the only one) ---
    #pragma unroll
    for (int it = 0; it < 4; it++)
        *(bf16x8*)&w1lds[it*4096 + tid*8] = wtmp[it];
    __syncthreads();

    // --- layer0: ea @ W0c (B-frags from global/L1) ---
    f32x4 acc[8] = {};
    #pragma unroll
    for (int kt = 0; kt < 4; kt++) {
        #pragma unroll
        for (int nt = 0; nt < 8; nt++) {
            bf16x8 bfr = w0c[(size_t)(kt*8 + nt)*64 + lane];
            acc[nt] = __builtin_amdgcn_mfma_f32_16x16x32_bf16(eafrag[kt], bfr, acc[nt], 0, 0, 0);
        }
    }

    // --- bias + PQ add + ELU; hidden in place (lane-owned) ---
    #pragma unroll
    for (int nt = 0; nt < 8; nt++) {
        int col = nt*16 + l15;
        float bb = b0[col];
        #pragma unroll
        for (int j = 0; j < 4; j++) {
            int r = lg*4 + j;
            float v = acc[nt][j] + bb + bf2f(pq[wave][r][col]);
            v = v > 0.f ? v : (__expf(v) - 1.f);
            pq[wave][r][col] = f2bf(v);
        }
    }
    LGKM0();   // hidden visible to all lanes of this wave

    // --- layer1: hid @ W1 (B-frags from LDS) ---
    f32x4 acc2[8] = {};
    #pragma unroll
    for (int kt = 0; kt < 4; kt++) {
        bf16x8 af = *(const bf16x8*)&pq[wave][l15][kt*32 + lg*8];
        #pragma unroll
        for (int nt = 0; nt < 8; nt++) {
            bf16x8 bfr = *(const bf16x8*)&w1lds[((kt*8 + nt)*64 + lane)*8];
            acc2[nt] = __builtin_amdgcn_mfma_f32_16x16x32_bf16(af, bfr, acc2[nt], 0, 0, 0);
        }
    }
    LGKM0();   // hidden ds_reads drained -> tile reusable

    // --- stage ea fragments (residual source) ---
    #pragma unroll
    for (int kt = 0; kt < 4; kt++)
        *(bf16x8*)&pq[wave][l15][kt*32 + lg*8] = eafrag[kt];
    LGKM0();

    // --- residual (LDS) + LayerNorm ---
    float t[8][4];
    #pragma unroll
    for (int nt = 0; nt < 8; nt++) {
        int col = nt*16 + l15;
        float bb = b1[col];
        #pragma unroll
        for (int j = 0; j < 4; j++) {
            int r = lg*4 + j;
            t[nt][j] = acc2[nt][j] + bb + bf2f(pq[wave][r][col]);
        }
    }
    LGKM0();   // all residual reads done -> tile reusable for output staging

    #pragma unroll
    for (int j = 0; j < 4; j++) {
        float s = 0.f;
        #pragma unroll
        for (int nt = 0; nt < 8; nt++) s += t[nt][j];
        #pragma unroll
        for (int m = 1; m < 16; m <<= 1) s += __shfl_xor(s, m);
        float mean = s * (1.0f / 128.0f);
        float s2 = 0.f;
        #pragma unroll
        for (int nt = 0; nt < 8; nt++) { float d = t[nt][j] - mean; s2 += d*d; }
        #pragma unroll
        for (int m = 1; m < 16; m <<= 1) s2 += __shfl_xor(s2, m);
        float rstd = rsqrtf(s2 * (1.0f / 128.0f) + 1e-5f);
        int r = lg*4 + j;
        #pragma unroll
        for (int nt = 0; nt < 8; nt++) {
            int col = nt*16 + l15;
            pq[wave][r][col] = f2bf((t[nt][j] - mean) * rstd * lng[col] + lnb[col]);
        }
    }
    LGKM0();   // LN output staged (wave-local)

    // --- wide coalesced store: wave streams its 16 rows (4KB) ---
    #pragma unroll
    for (int k = 0; k < 4; k++) {
        int row = k*4 + (lane >> 4);
        long long erow = ebase + row;
        bf16x8 vv = *(const bf16x8*)&pq[wave][row][l15*8];
        if (erow < N_EDGES)
            *(bf16x8*)&ea_out[erow*128 + l15*8] = vv;
    }
}

// ---------------------------------------------------------------------------
// Aggregation: one wave per node; ea rows for node n are CONTIGUOUS
// [off[n], off[n+1]) in the permuted layout -> pure streaming read.
// ---------------------------------------------------------------------------
__global__ __launch_bounds__(256)
void agg_kernel(const short* __restrict__ ea,
                const int* __restrict__ off,
                short* __restrict__ aggb) {
    const int wid  = (blockIdx.x * 256 + threadIdx.x) >> 6;
    const int lane = threadIdx.x & 63;
    if (wid >= N_NODES) return;
    const int o0 = off[wid], o1 = off[wid + 1];
    float s0 = 0.f, s1 = 0.f;
    for (int i = o0; i < o1; i++) {
        unsigned int v = *(const unsigned int*)(ea + (long long)i*128 + lane*2);
        s0 += __uint_as_float(v << 16);
        s1 += __uint_as_float(v & 0xFFFF0000u);
    }
    float inv = (o1 > o0) ? 1.f / (float)(o1 - o0) : 0.f;
    short2 w;
    w.x = f2bf(s0 * inv);
    w.y = f2bf(s1 * inv);
    *(short2*)(aggb + (long long)wid*128 + lane*2) = w;
}

// ---------------------------------------------------------------------------
// Node kernel + fused P/Q production. x kept bf16 between iterations.
// All bulk outputs (x bf16, P, Q) leave via wide dwordx4 stores staged
// through LDS tiles; P/Q use a second tile so x (in hid) stays live.
// ---------------------------------------------------------------------------
template<bool XF32IN, bool XF32OUT, bool MAKEPQ>
__global__ __launch_bounds__(256)
void node_kernel(const float* __restrict__ xf_in,
                 const short* __restrict__ xb_in,
                 float* __restrict__ xf_out,
                 short* __restrict__ xb_out,
                 const short* __restrict__ aggb,
                 const short* __restrict__ w0p,
                 const short* __restrict__ w1p,
                 const short* __restrict__ wnext,
                 short* __restrict__ P,
                 short* __restrict__ Q,
                 const float* __restrict__ b0,
                 const float* __restrict__ b1,
                 const float* __restrict__ lng,
                 const float* __restrict__ lnb) {
    __shared__ __align__(16) short hid[4][16][140];
    __shared__ __align__(16) short outt[4][16][140];
    const int tid  = threadIdx.x;
    const int wave = tid >> 6, lane = tid & 63;
    const int l15  = lane & 15, lg = lane >> 4;
    const long long nbase = (long long)blockIdx.x * 64 + wave * 16;
    long long arow = nbase + l15;
    if (arow >= N_NODES) arow = N_NODES - 1;

    f32x4 acc[8] = {};
    const bf16x8* w0f = (const bf16x8*)w0p;
    #pragma unroll
    for (int kt = 0; kt < 8; kt++) {
        int k0 = kt*32 + lg*8;
        bf16x8 af;
        if (k0 < 128) {
            if (XF32IN) {
                const float* ap = xf_in + arow*128 + k0;
                float4 f0 = *(const float4*)ap;
                float4 f1 = *(const float4*)(ap + 4);
                af[0]=f2bf(f0.x); af[1]=f2bf(f0.y); af[2]=f2bf(f0.z); af[3]=f2bf(f0.w);
                af[4]=f2bf(f1.x); af[5]=f2bf(f1.y); af[6]=f2bf(f1.z); af[7]=f2bf(f1.w);
            } else {
                af = *(const bf16x8*)(xb_in + arow*128 + k0);
            }
        } else {
            af = *(const bf16x8*)(aggb + arow*128 + (k0 - 128));
        }
        #pragma unroll
        for (int nt = 0; nt < 8; nt++) {
            bf16x8 bfr = w0f[(size_t)(kt*8 + nt)*64 + lane];
            acc[nt] = __builtin_amdgcn_mfma_f32_16x16x32_bf16(af, bfr, acc[nt], 0, 0, 0);
        }
    }
    #pragma unroll
    for (int nt = 0; nt < 8; nt++) {
        int col = nt*16 + l15;
        float bb = b0[col];
        #pragma unroll
        for (int j = 0; j < 4; j++) {
            float v = acc[nt][j] + bb;
            v = v > 0.f ? v : (__expf(v) - 1.f);
            hid[wave][lg*4 + j][col] = f2bf(v);
        }
    }
    LGKM0();   // hid writes complete (wave-local)

    f32x4 acc2[8] = {};
    const bf16x8* w1f = (const bf16x8*)w1p;
    #pragma unroll
    for (int kt = 0; kt < 4; kt++) {
        bf16x8 af = *(const bf16x8*)&hid[wave][l15][kt*32 + lg*8];
        #pragma unroll
        for (int nt = 0; nt < 8; nt++) {
            bf16x8 bfr = w1f[(size_t)(kt*8 + nt)*64 + lane];
            acc2[nt] = __builtin_amdgcn_mfma_f32_16x16x32_bf16(af, bfr, acc2[nt], 0, 0, 0);
        }
    }
    float t[8][4];
    #pragma unroll
    for (int nt = 0; nt < 8; nt++) {
        int col = nt*16 + l15;
        float bb = b1[col];
        #pragma unroll
        for (int j = 0; j < 4; j++) {
            long long nrow = nbase + lg*4 + j;
            long long nrc  = nrow < N_NODES ? nrow : (N_NODES - 1);
            float res = XF32IN ? xf_in[nrc*128 + col] : bf2f(xb_in[nrc*128 + col]);
            t[nt][j] = acc2[nt][j] + bb + res;
        }
    }
    float xo[8][4];
    #pragma unroll
    for (int j = 0; j < 4; j++) {
        float s = 0.f;
        #pragma unroll
        for (int nt = 0; nt < 8; nt++) s += t[nt][j];
        #pragma unroll
        for (int m = 1; m < 16; m <<= 1) s += __shfl_xor(s, m);
        float mean = s * (1.0f / 128.0f);
        float s2 = 0.f;
        #pragma unroll
        for (int nt = 0; nt < 8; nt++) { float d = t[nt][j] - mean; s2 += d*d; }
        #pragma unroll
        for (int m = 1; m < 16; m <<= 1) s2 += __shfl_xor(s2, m);
        float rstd = rsqrtf(s2 * (1.0f / 128.0f) + 1e-5f);
        long long nrow = nbase + lg*4 + j;
        #pragma unroll
        for (int nt = 0; nt < 8; nt++) {
            int col = nt*16 + l15;
            float v = (t[nt][j] - mean) * rstd * lng[col] + lnb[col];
            xo[nt][j] = v;
            if (XF32OUT && nrow < N_NODES) xf_out[nrow*128 + col] = v;
        }
    }

    if (!XF32OUT || MAKEPQ) {
        // stage LN'd x (bf16) into drained hid tile
        LGKM0();   // layer1 ds_reads drained
        #pragma unroll
        for (int nt = 0; nt < 8; nt++) {
            int col = nt*16 + l15;
            #pragma unroll
            for (int j = 0; j < 4; j++)
                hid[wave][lg*4 + j][col] = f2bf(xo[nt][j]);
        }
        LGKM0();
    }

    if (!XF32OUT) {
        // wide coalesced bf16 x store: wave streams its 16 rows (4KB)
        #pragma unroll
        for (int k = 0; k < 4; k++) {
            int row = k*4 + (lane >> 4);
            long long nrow = nbase + row;
            bf16x8 vv = *(const bf16x8*)&hid[wave][row][l15*8];
            if (nrow < N_NODES)
                *(bf16x8*)&xb_out[nrow*128 + l15*8] = vv;
        }
    }

    if (MAKEPQ) {
        const bf16x8* wn = (const bf16x8*)wnext;
        // ---- P = x @ W0a' (x from hid), wide store via outt ----
        {
            f32x4 accP[8] = {};
            #pragma unroll
            for (int kt = 0; kt < 4; kt++) {
                bf16x8 af = *(const bf16x8*)&hid[wave][l15][kt*32 + lg*8];
                #pragma unroll
                for (int nt = 0; nt < 8; nt++)
                    accP[nt] = __builtin_amdgcn_mfma_f32_16x16x32_bf16(af, wn[(size_t)(kt*8 + nt)*64 + lane], accP[nt], 0, 0, 0);
            }
            LGKM0();
            #pragma unroll
            for (int nt = 0; nt < 8; nt++) {
                int col = nt*16 + l15;
                #pragma unroll
                for (int j = 0; j < 4; j++)
                    outt[wave][lg*4 + j][col] = f2bf(accP[nt][j]);
            }
            LGKM0();
            #pragma unroll
            for (int k = 0; k < 4; k++) {
                int row = k*4 + (lane >> 4);
                long long nrow = nbase + row;
                bf16x8 vv = *(const bf16x8*)&outt[wave][row][l15*8];
                if (nrow < N_NODES)
                    *(bf16x8*)&P[nrow*128 + l15*8] = vv;
            }
            LGKM0();   // outt reads done -> reusable
        }
        // ---- Q = x @ W0b' (x from hid), wide store via outt ----
        {
            f32x4 accQ[8] = {};
            #pragma unroll
            for (int kt = 0; kt < 4; kt++) {
                bf16x8 af = *(const bf16x8*)&hid[wave][l15][kt*32 + lg*8];
                #pragma unroll
                for (int nt = 0; nt < 8; nt++)
                    accQ[nt] = __builtin_amdgcn_mfma_f32_16x16x32_bf16(af, wn[(size_t)((kt+4)*8 + nt)*64 + lane], accQ[nt], 0, 0, 0);
            }
            LGKM0();
            #pragma unroll
            for (int nt = 0; nt < 8; nt++) {
                int col = nt*16 + l15;
                #pragma unroll
                for (int j = 0; j < 4; j++)
                    outt[wave][lg*4 + j][col] = f2bf(accQ[nt][j]);
            }
            LGKM0();
            #pragma unroll
            for (int k = 0; k < 4; k++) {
                int row = k*4 + (lane >> 4);
                long long nrow = nbase + row;
                bf16x8 vv = *(const bf16x8*)&outt[wave][row][l15*8];
                if (nrow < N_NODES)
                    *(bf16x8*)&Q[nrow*128 + l15*8] = vv;
            }
        }
    }
}

extern "C" void kernel_launch(void* const* d_in, const int* in_sizes, int n_in,
                              void* d_out, int out_size, void* d_ws, size_t ws_size,
                              hipStream_t stream) {
    const float* x_in   = (const float*)d_in[0];
    const int*   eidx   = (const int*)d_in[1];
    const float* ea_in0 = (const float*)d_in[2];
    const float* ew0  = (const float*)d_in[5];
    const float* eb0  = (const float*)d_in[6];
    const float* ew1  = (const float*)d_in[7];
    const float* eb1  = (const float*)d_in[8];
    const float* elng = (const float*)d_in[9];
    const float* elnb = (const float*)d_in[10];
    const float* nw0  = (const float*)d_in[11];
    const float* nb0  = (const float*)d_in[12];
    const float* nw1  = (const float*)d_in[13];
    const float* nb1  = (const float*)d_in[14];
    const float* nlng = (const float*)d_in[15];
    const float* nlnb = (const float*)d_in[16];
    const int* srcI = eidx;
    const int* tgtI = eidx + N_EDGES;

    // ---- workspace layout (bytes) ----
    char* ws = (char*)d_ws;
    size_t o = 0;
    short* ea_bf  = (short*)(ws + o); o += (size_t)N_EDGES * 128 * 2;       // 153.6 MB (permuted)
    short* Pb     = (short*)(ws + o); o += (size_t)N_NODES * 128 * 2;       // 25.6 MB
    short* Qb     = (short*)(ws + o); o += (size_t)N_NODES * 128 * 2;       // 25.6 MB
    short* aggb   = (short*)(ws + o); o += (size_t)N_NODES * 128 * 2;       // 25.6 MB
    short* xbA    = (short*)(ws + o); o += (size_t)N_NODES * 128 * 2;       // 25.6 MB
    short* xbB    = (short*)(ws + o); o += (size_t)N_NODES * 128 * 2;       // 25.6 MB
    short* wpack  = (short*)(ws + o); o += (size_t)NMP * 114688 * 2;        // 0.92 MB
    int*   deg    = (int*)(ws + o);   o += (size_t)N_NODES * 4;
    int*   offA   = (int*)(ws + o);   o += (size_t)(N_NODES + 1) * 4;
    int*   cursor = (int*)(ws + o);   o += (size_t)N_NODES * 4;
    int*   bsum   = (int*)(ws + o);   o += (size_t)NB_SCAN * 4;
    int*   bbase  = (int*)(ws + o);   o += (size_t)NB_SCAN * 4;
    int*   elist  = (int*)(ws + o);   o += (size_t)N_EDGES * 4;
    int*   psrc   = (int*)(ws + o);   o += (size_t)N_EDGES * 4;
    int*   ptgt   = (int*)(ws + o);   o += (size_t)N_EDGES * 4;
    float* xbuf   = (float*)d_out;

    // ---- one-time: weight pack + CSR + permuted index arrays ----
    pack_weights<<<(NMP * 14336 + 255) / 256, 256, 0, stream>>>(ew0, ew1, nw0, nw1, wpack);
    hipMemsetAsync(deg, 0, (size_t)N_NODES * 4, stream);
    deg_count<<<(N_EDGES + 255) / 256, 256, 0, stream>>>(tgtI, deg);
    scan_reduce<<<NB_SCAN, 256, 0, stream>>>(deg, bsum);
    scan_top<<<1, 64, 0, stream>>>(bsum, bbase, offA);
    scan_apply<<<NB_SCAN, 256, 0, stream>>>(deg, bbase, offA, cursor);
    fill_csr<<<(N_EDGES + 255) / 256, 256, 0, stream>>>(tgtI, cursor, elist);
    build_perm<<<(N_EDGES + 255) / 256, 256, 0, stream>>>(srcI, tgtI, elist, psrc, ptgt);

    const int ngrid = (N_NODES + 63) / 64;
    const int egrid = (N_EDGES + 127) / 128;
    // iter-0 P/Q from input x
    xform_kernel<<<ngrid, 256, 0, stream>>>(x_in, Pb, Qb, wpack);

    // bf16 x ping-pong: iter0 writes xbA; iter1 xbA->xbB; iter2 xbB->xbA;
    // iter3 reads xbA, writes f32 d_out.
    short* xbin[4]  = {nullptr, xbA, xbB, xbA};
    short* xbout[4] = {xbA, xbB, xbA, nullptr};

    for (int i = 0; i < NMP; i++) {
        const short* wp = wpack + (size_t)i * 114688;
        const short* wnext = wpack + (size_t)(i + 1) * 114688;   // unused when i==3
        if (i == 0) {
            edge_kernel<true><<<egrid, 512, 0, stream>>>(
                Pb, Qb, (const void*)ea_in0, ea_bf, psrc, ptgt, elist,
                wp + 0,
                eb0 + i * 128, eb1 + i * 128, elng + i * 128, elnb + i * 128);
        } else {
            edge_kernel<false><<<egrid, 512, 0, stream>>>(
                Pb, Qb, (const void*)ea_bf, ea_bf, psrc, ptgt, elist,
                wp + 0,
                eb0 + i * 128, eb1 + i * 128, elng + i * 128, elnb + i * 128);
        }
        agg_kernel<<<(N_NODES * 64 + 255) / 256, 256, 0, stream>>>(ea_bf, offA, aggb);
        if (i == 0) {
            node_kernel<true, false, true><<<ngrid, 256, 0, stream>>>(
                x_in, nullptr, nullptr, xbout[i], aggb,
                wp + 65536, wp + 98304, wnext, Pb, Qb,
                nb0 + i * 128, nb1 + i * 128, nlng + i * 128, nlnb + i * 128);
        } else if (i < NMP - 1) {
            node_kernel<false, false, true><<<ngrid, 256, 0, stream>>>(
                nullptr, xbin[i], nullptr, xbout[i], aggb,
                wp + 65536, wp + 98304, wnext, Pb, Qb,
                nb0 + i * 128, nb1 + i * 128, nlng + i * 128, nlnb + i * 128);
        } else {
            node_kernel<false, true, false><<<ngrid, 256, 0, stream>>>(
                nullptr, xbin[i], xbuf, nullptr, aggb,
                wp + 65536, wp + 98304, wnext, Pb, Qb,
                nb0 + i * 128, nb1 + i * 128, nlng + i * 128, nlnb + i * 128);
        }
    }
}

// Round 17
// 1041.126 us; speedup vs baseline: 1.4147x; 1.0875x over previous
//
#include <hip/hip_runtime.h>
#include <hip/hip_bf16.h>

#define N_NODES 100000
#define N_EDGES 600000
#define NMP     4
#define NB_SCAN 391   // ceil(N_NODES/256)

typedef __attribute__((ext_vector_type(8))) short bf16x8;
typedef __attribute__((ext_vector_type(4))) float f32x4;

#define LGKM0() asm volatile("s_waitcnt lgkmcnt(0)" ::: "memory")

// Hardware RNE convert (compiler emits v_cvt_pk_bf16_f32).
__device__ __forceinline__ short f2bf(float f) {
    union { __hip_bfloat16 h; short s; } u;
    u.h = __float2bfloat16(f);
    return u.s;
}
__device__ __forceinline__ float bf2f(short s) {
    return __uint_as_float(((unsigned int)(unsigned short)s) << 16);
}

// ---------------------------------------------------------------------------
// Pack weights [K][128] f32 -> MFMA B-fragment order bf16:
// frag(kt,nt,lane)[j] = W[kt*32 + (lane>>4)*8 + j][nt*16 + (lane&15)]
// Per-iter packed layout (elems): edge_w0 @0 (49152), edge_w1 @49152 (16384),
// node_w0 @65536 (32768), node_w1 @98304 (16384); iter stride 114688.
// W0c (ea part, kt 8..11) = elems [32768,49152); W1 = [49152,65536).
// ---------------------------------------------------------------------------
__global__ void pack_weights(const float* __restrict__ ew0, const float* __restrict__ ew1,
                             const float* __restrict__ nw0, const float* __restrict__ nw1,
                             short* __restrict__ out) {
    int t = blockIdx.x * blockDim.x + threadIdx.x;
    if (t >= NMP * 14336) return;
    int it = t / 14336;
    int r  = t % 14336;
    const float* W; int obase;
    if (r < 6144)       { W = ew0 + (size_t)it*384*128; obase = 0;     }
    else if (r < 8192)  { W = ew1 + (size_t)it*128*128; obase = 49152; r -= 6144;  }
    else if (r < 12288) { W = nw0 + (size_t)it*256*128; obase = 65536; r -= 8192;  }
    else                { W = nw1 + (size_t)it*128*128; obase = 98304; r -= 12288; }
    int kt   = r >> 9;
    int rem  = r & 511;
    int nt   = rem >> 6;
    int lane = rem & 63;
    short* o = out + (size_t)it*114688 + obase + ((size_t)(kt*8 + nt)*64 + lane)*8;
    int kbase = kt*32 + (lane >> 4)*8;
    int n     = nt*16 + (lane & 15);
    #pragma unroll
    for (int j = 0; j < 8; j++) o[j] = f2bf(W[(size_t)(kbase + j)*128 + n]);
}

// ------------------------- CSR build (once per launch) ----------------------
__global__ void deg_count(const int* __restrict__ tgt, int* __restrict__ deg) {
    int e = blockIdx.x * blockDim.x + threadIdx.x;
    if (e < N_EDGES) atomicAdd(&deg[tgt[e]], 1);
}

__global__ void scan_reduce(const int* __restrict__ deg, int* __restrict__ bsum) {
    __shared__ int sh[256];
    int i = blockIdx.x * 256 + threadIdx.x;
    sh[threadIdx.x] = (i < N_NODES) ? deg[i] : 0;
    __syncthreads();
    for (int d = 128; d > 0; d >>= 1) {
        if (threadIdx.x < d) sh[threadIdx.x] += sh[threadIdx.x + d];
        __syncthreads();
    }
    if (threadIdx.x == 0) bsum[blockIdx.x] = sh[0];
}

__global__ void scan_top(const int* __restrict__ bsum, int* __restrict__ bbase,
                         int* __restrict__ off) {
    if (threadIdx.x == 0 && blockIdx.x == 0) {
        int run = 0;
        for (int b = 0; b < NB_SCAN; b++) { bbase[b] = run; run += bsum[b]; }
        off[N_NODES] = run;
    }
}

__global__ void scan_apply(const int* __restrict__ deg, const int* __restrict__ bbase,
                           int* __restrict__ off, int* __restrict__ cursor) {
    __shared__ int sh[256];
    int i = blockIdx.x * 256 + threadIdx.x;
    int v = (i < N_NODES) ? deg[i] : 0;
    sh[threadIdx.x] = v;
    __syncthreads();
    int acc = v;
    for (int d = 1; d < 256; d <<= 1) {
        int t = (threadIdx.x >= d) ? sh[threadIdx.x - d] : 0;
        __syncthreads();
        acc += t;
        sh[threadIdx.x] = acc;
        __syncthreads();
    }
    if (i < N_NODES) {
        int o = bbase[blockIdx.x] + acc - v;   // exclusive
        off[i] = o;
        cursor[i] = o;
    }
}

__global__ void fill_csr(const int* __restrict__ tgt, int* __restrict__ cursor,
                         int* __restrict__ elist) {
    int e = blockIdx.x * blockDim.x + threadIdx.x;
    if (e < N_EDGES) {
        int p = atomicAdd(&cursor[tgt[e]], 1);
        elist[p] = e;
    }
}

// psrc/ptgt: src/tgt per SORTED edge position
__global__ void build_perm(const int* __restrict__ srcI, const int* __restrict__ tgtI,
                           const int* __restrict__ elist,
                           int* __restrict__ psrc, int* __restrict__ ptgt) {
    int k = blockIdx.x * blockDim.x + threadIdx.x;
    if (k < N_EDGES) {
        int e = elist[k];
        psrc[k] = srcI[e];
        ptgt[k] = tgtI[e];
    }
}

// ---------------------------------------------------------------------------
// xform: P = x@W0a, Q = x@W0b  (bf16, wide-store via LDS staging) — iter 0.
// ---------------------------------------------------------------------------
__global__ __launch_bounds__(256)
void xform_kernel(const float* __restrict__ x_in,
                  short* __restrict__ P, short* __restrict__ Q,
                  const short* __restrict__ w0p) {
    __shared__ __align__(16) short outt[4][16][140];
    const int tid  = threadIdx.x;
    const int wave = tid >> 6, lane = tid & 63;
    const int l15  = lane & 15, lg = lane >> 4;
    const long long nbase = (long long)blockIdx.x * 64 + wave * 16;
    long long arow = nbase + l15;
    if (arow >= N_NODES) arow = N_NODES - 1;

    f32x4 accP[8] = {}, accQ[8] = {};
    const bf16x8* w0f = (const bf16x8*)w0p;
    #pragma unroll
    for (int kt = 0; kt < 4; kt++) {
        const float* ap = x_in + arow*128 + kt*32 + lg*8;
        float4 f0 = *(const float4*)ap;
        float4 f1 = *(const float4*)(ap + 4);
        bf16x8 af;
        af[0]=f2bf(f0.x); af[1]=f2bf(f0.y); af[2]=f2bf(f0.z); af[3]=f2bf(f0.w);
        af[4]=f2bf(f1.x); af[5]=f2bf(f1.y); af[6]=f2bf(f1.z); af[7]=f2bf(f1.w);
        #pragma unroll
        for (int nt = 0; nt < 8; nt++) {
            accP[nt] = __builtin_amdgcn_mfma_f32_16x16x32_bf16(af, w0f[(size_t)(kt*8 + nt)*64 + lane], accP[nt], 0, 0, 0);
            accQ[nt] = __builtin_amdgcn_mfma_f32_16x16x32_bf16(af, w0f[(size_t)((kt+4)*8 + nt)*64 + lane], accQ[nt], 0, 0, 0);
        }
    }
    // stage P -> wide store
    #pragma unroll
    for (int nt = 0; nt < 8; nt++) {
        int col = nt*16 + l15;
        #pragma unroll
        for (int j = 0; j < 4; j++)
            outt[wave][lg*4 + j][col] = f2bf(accP[nt][j]);
    }
    LGKM0();
    #pragma unroll
    for (int k = 0; k < 4; k++) {
        int row = k*4 + (lane >> 4);
        long long nrow = nbase + row;
        bf16x8 vv = *(const bf16x8*)&outt[wave][row][l15*8];
        if (nrow < N_NODES)
            *(bf16x8*)&P[nrow*128 + l15*8] = vv;
    }
    LGKM0();   // store-source reads done -> tile reusable
    // stage Q -> wide store
    #pragma unroll
    for (int nt = 0; nt < 8; nt++) {
        int col = nt*16 + l15;
        #pragma unroll
        for (int j = 0; j < 4; j++)
            outt[wave][lg*4 + j][col] = f2bf(accQ[nt][j]);
    }
    LGKM0();
    #pragma unroll
    for (int k = 0; k < 4; k++) {
        int row = k*4 + (lane >> 4);
        long long nrow = nbase + row;
        bf16x8 vv = *(const bf16x8*)&outt[wave][row][l15*8];
        if (nrow < N_NODES)
            *(bf16x8*)&Q[nrow*128 + l15*8] = vv;
    }
}

// ---------------------------------------------------------------------------
// Edge kernel — r9 structure (best measured: 190 us):
// 512 threads (8 waves), 128 edges/block, CSR-sorted edges.
// LDS 67.8KB -> 2 blocks/CU: W1 staged in LDS (32KB), W0c B-frags from
// global/L2. Wide dwordx4 epilogue stores via per-wave pq tile staging.
// ---------------------------------------------------------------------------
template<bool EAF32>
__global__ __launch_bounds__(512)
void edge_kernel(const short* __restrict__ P,
                 const short* __restrict__ Q,
                 const void* __restrict__ ea_in_v,
                 short* __restrict__ ea_out,
                 const int* __restrict__ psrc,
                 const int* __restrict__ ptgt,
                 const int* __restrict__ elist,
                 const short* __restrict__ w0p,
                 const float* __restrict__ b0,
                 const float* __restrict__ b1,
                 const float* __restrict__ lng,
                 const float* __restrict__ lnb) {
    __shared__ __align__(16) short w1lds[16384];     // 32KB: W1
    __shared__ __align__(16) short pq[8][16][140];   // 35840B per-wave tiles
    const int tid  = threadIdx.x;
    const int wave = tid >> 6, lane = tid & 63;
    const int l15  = lane & 15, lg = lane >> 4;
    const long long ebase = (long long)blockIdx.x * 128 + wave * 16;
    const long long arow  = ebase + l15;
    const long long arc   = arow < N_EDGES ? arow : (N_EDGES - 1);
    const float* eaf = (const float*)ea_in_v;
    const short* eab = (const short*)ea_in_v;
    const bf16x8* w0c = (const bf16x8*)(w0p + 32768);   // W0c frags via L1/L2

    // --- issue W1 loads (32KB contiguous at w0p+49152) ---
    const short* w1src = w0p + 49152;
    bf16x8 wtmp[4];
    #pragma unroll
    for (int it = 0; it < 4; it++)
        wtmp[it] = *(const bf16x8*)(w1src + it*4096 + tid*8);

    // --- per-wave gather: P[psrc]+Q[ptgt] summed in registers ---
    {
        const int c8 = (lane & 7) * 16;        // 32B column chunk (shorts)
        #pragma unroll
        for (int pass = 0; pass < 2; pass++) {
            int rr = (lane >> 3) + pass * 8;
            long long e = ebase + rr;
            if (e >= N_EDGES) e = N_EDGES - 1;
            long long s = psrc[e], t = ptgt[e];
            bf16x8 p0 = *(const bf16x8*)(P + s*128 + c8);
            bf16x8 p1 = *(const bf16x8*)(P + s*128 + c8 + 8);
            bf16x8 q0 = *(const bf16x8*)(Q + t*128 + c8);
            bf16x8 q1 = *(const bf16x8*)(Q + t*128 + c8 + 8);
            bf16x8 u0, u1;
            #pragma unroll
            for (int k = 0; k < 8; k++) {
                u0[k] = f2bf(bf2f(p0[k]) + bf2f(q0[k]));
                u1[k] = f2bf(bf2f(p1[k]) + bf2f(q1[k]));
            }
            *(bf16x8*)&pq[wave][rr][c8]     = u0;
            *(bf16x8*)&pq[wave][rr][c8 + 8] = u1;
        }
    }

    // --- load ea fragments (A-operand + residual) ---
    bf16x8 eafrag[4];
    #pragma unroll
    for (int kt = 0; kt < 4; kt++) {
        if (EAF32) {
            long long orig = elist[arc];          // one-time scatter at iter 0
            const float* ap = eaf + orig*128 + kt*32 + lg*8;
            float4 f0 = *(const float4*)ap;
            float4 f1 = *(const float4*)(ap + 4);
            bf16x8 af;
            af[0]=f2bf(f0.x); af[1]=f2bf(f0.y); af[2]=f2bf(f0.z); af[3]=f2bf(f0.w);
            af[4]=f2bf(f1.x); af[5]=f2bf(f1.y); af[6]=f2bf(f1.z); af[7]=f2bf(f1.w);
            eafrag[kt] = af;
        } else {
            eafrag[kt] = *(const bf16x8*)(eab + arc*128 + kt*32 + lg*8);
        }
    }

    // --- commit W1 to LDS, block barrier (the only one) ---
    #pragma unroll
    for (int it = 0; it < 4; it++)
        *(bf16x8*)&w1lds[it*4096 + tid*8] = wtmp[it];
    __syncthreads();

    // --- layer0: ea @ W0c (B-frags from global/L1) ---
    f32x4 acc[8] = {};
    #pragma unroll
    for (int kt = 0; kt < 4; kt++) {
        #pragma unroll
        for (int nt = 0; nt < 8; nt++) {
            bf16x8 bfr = w0c[(size_t)(kt*8 + nt)*64 + lane];
            acc[nt] = __builtin_amdgcn_mfma_f32_16x16x32_bf16(eafrag[kt], bfr, acc[nt], 0, 0, 0);
        }
    }

    // --- bias + PQ add + ELU; hidden in place (lane-owned) ---
    #pragma unroll
    for (int nt = 0; nt < 8; nt++) {
        int col = nt*16 + l15;
        float bb = b0[col];
        #pragma unroll
        for (int j = 0; j < 4; j++) {
            int r = lg*4 + j;
            float v = acc[nt][j] + bb + bf2f(pq[wave][r][col]);
            v = v > 0.f ? v : (__expf(v) - 1.f);
            pq[wave][r][col] = f2bf(v);
        }
    }
    LGKM0();   // hidden visible to all lanes of this wave

    // --- layer1: hid @ W1 (B-frags from LDS) ---
    f32x4 acc2[8] = {};
    #pragma unroll
    for (int kt = 0; kt < 4; kt++) {
        bf16x8 af = *(const bf16x8*)&pq[wave][l15][kt*32 + lg*8];
        #pragma unroll
        for (int nt = 0; nt < 8; nt++) {
            bf16x8 bfr = *(const bf16x8*)&w1lds[((kt*8 + nt)*64 + lane)*8];
            acc2[nt] = __builtin_amdgcn_mfma_f32_16x16x32_bf16(af, bfr, acc2[nt], 0, 0, 0);
        }
    }
    LGKM0();   // hidden ds_reads drained -> tile reusable

    // --- stage ea fragments (residual source) ---
    #pragma unroll
    for (int kt = 0; kt < 4; kt++)
        *(bf16x8*)&pq[wave][l15][kt*32 + lg*8] = eafrag[kt];
    LGKM0();

    // --- residual (LDS) + LayerNorm ---
    float t[8][4];
    #pragma unroll
    for (int nt = 0; nt < 8; nt++) {
        int col = nt*16 + l15;
        float bb = b1[col];
        #pragma unroll
        for (int j = 0; j < 4; j++) {
            int r = lg*4 + j;
            t[nt][j] = acc2[nt][j] + bb + bf2f(pq[wave][r][col]);
        }
    }
    LGKM0();   // all residual reads done -> tile reusable for output staging

    #pragma unroll
    for (int j = 0; j < 4; j++) {
        float s = 0.f;
        #pragma unroll
        for (int nt = 0; nt < 8; nt++) s += t[nt][j];
        #pragma unroll
        for (int m = 1; m < 16; m <<= 1) s += __shfl_xor(s, m);
        float mean = s * (1.0f / 128.0f);
        float s2 = 0.f;
        #pragma unroll
        for (int nt = 0; nt < 8; nt++) { float d = t[nt][j] - mean; s2 += d*d; }
        #pragma unroll
        for (int m = 1; m < 16; m <<= 1) s2 += __shfl_xor(s2, m);
        float rstd = rsqrtf(s2 * (1.0f / 128.0f) + 1e-5f);
        int r = lg*4 + j;
        #pragma unroll
        for (int nt = 0; nt < 8; nt++) {
            int col = nt*16 + l15;
            pq[wave][r][col] = f2bf((t[nt][j] - mean) * rstd * lng[col] + lnb[col]);
        }
    }
    LGKM0();   // LN output staged (wave-local)

    // --- wide coalesced store: wave streams its 16 rows (4KB) ---
    #pragma unroll
    for (int k = 0; k < 4; k++) {
        int row = k*4 + (lane >> 4);
        long long erow = ebase + row;
        bf16x8 vv = *(const bf16x8*)&pq[wave][row][l15*8];
        if (erow < N_EDGES)
            *(bf16x8*)&ea_out[erow*128 + l15*8] = vv;
    }
}

// ---------------------------------------------------------------------------
// Node kernel with FUSED aggregation + P/Q production. x kept bf16 between
// iterations. Aggregation: tgt-sorted layout makes each wave's 16 nodes own
// a contiguous ea span; 8 lanes/node x 16 cols sum deg rows in f32, mean,
// stage bf16 into outt -> layer-0 A-frags read from LDS. outt is later
// reused for the P/Q wide-store staging.
// ---------------------------------------------------------------------------
template<bool XF32IN, bool XF32OUT, bool MAKEPQ>
__global__ __launch_bounds__(256)
void node_kernel(const float* __restrict__ xf_in,
                 const short* __restrict__ xb_in,
                 float* __restrict__ xf_out,
                 short* __restrict__ xb_out,
                 const short* __restrict__ ea,
                 const int* __restrict__ off,
                 const short* __restrict__ w0p,
                 const short* __restrict__ w1p,
                 const short* __restrict__ wnext,
                 short* __restrict__ P,
                 short* __restrict__ Q,
                 const float* __restrict__ b0,
                 const float* __restrict__ b1,
                 const float* __restrict__ lng,
                 const float* __restrict__ lnb) {
    __shared__ __align__(16) short hid[4][16][140];
    __shared__ __align__(16) short outt[4][16][140];
    const int tid  = threadIdx.x;
    const int wave = tid >> 6, lane = tid & 63;
    const int l15  = lane & 15, lg = lane >> 4;
    const long long nbase = (long long)blockIdx.x * 64 + wave * 16;
    long long arow = nbase + l15;
    if (arow >= N_NODES) arow = N_NODES - 1;

    // --- fused aggregation: outt[wave][nl][c] = mean of ea rows of node ---
    {
        const int sub = lane >> 3;          // node-in-group 0..7
        const int cb  = (lane & 7) * 16;    // col base (shorts)
        #pragma unroll
        for (int pass = 0; pass < 2; pass++) {
            int nl = pass * 8 + sub;        // wave-local node row 0..15
            long long n = nbase + nl;
            if (n >= N_NODES) n = N_NODES - 1;
            int o0 = off[n], o1 = off[n + 1];
            float sums[16];
            #pragma unroll
            for (int c = 0; c < 16; c++) sums[c] = 0.f;
            for (int i = o0; i < o1; i++) {
                bf16x8 v0 = *(const bf16x8*)(ea + (long long)i*128 + cb);
                bf16x8 v1 = *(const bf16x8*)(ea + (long long)i*128 + cb + 8);
                #pragma unroll
                for (int c = 0; c < 8; c++) {
                    sums[c]     += bf2f(v0[c]);
                    sums[c + 8] += bf2f(v1[c]);
                }
            }
            float inv = (o1 > o0) ? 1.f / (float)(o1 - o0) : 0.f;
            bf16x8 wv0, wv1;
            #pragma unroll
            for (int c = 0; c < 8; c++) {
                wv0[c] = f2bf(sums[c] * inv);
                wv1[c] = f2bf(sums[c + 8] * inv);
            }
            *(bf16x8*)&outt[wave][nl][cb]     = wv0;
            *(bf16x8*)&outt[wave][nl][cb + 8] = wv1;
        }
    }
    LGKM0();   // agg tile visible to all lanes of this wave

    f32x4 acc[8] = {};
    const bf16x8* w0f = (const bf16x8*)w0p;
    #pragma unroll
    for (int kt = 0; kt < 8; kt++) {
        int k0 = kt*32 + lg*8;
        bf16x8 af;
        if (k0 < 128) {
            if (XF32IN) {
                const float* ap = xf_in + arow*128 + k0;
                float4 f0 = *(const float4*)ap;
                float4 f1 = *(const float4*)(ap + 4);
                af[0]=f2bf(f0.x); af[1]=f2bf(f0.y); af[2]=f2bf(f0.z); af[3]=f2bf(f0.w);
                af[4]=f2bf(f1.x); af[5]=f2bf(f1.y); af[6]=f2bf(f1.z); af[7]=f2bf(f1.w);
            } else {
                af = *(const bf16x8*)(xb_in + arow*128 + k0);
            }
        } else {
            af = *(const bf16x8*)&outt[wave][l15][k0 - 128];
        }
        #pragma unroll
        for (int nt = 0; nt < 8; nt++) {
            bf16x8 bfr = w0f[(size_t)(kt*8 + nt)*64 + lane];
            acc[nt] = __builtin_amdgcn_mfma_f32_16x16x32_bf16(af, bfr, acc[nt], 0, 0, 0);
        }
    }
    #pragma unroll
    for (int nt = 0; nt < 8; nt++) {
        int col = nt*16 + l15;
        float bb = b0[col];
        #pragma unroll
        for (int j = 0; j < 4; j++) {
            float v = acc[nt][j] + bb;
            v = v > 0.f ? v : (__expf(v) - 1.f);
            hid[wave][lg*4 + j][col] = f2bf(v);
        }
    }
    LGKM0();   // hid writes complete (wave-local)

    f32x4 acc2[8] = {};
    const bf16x8* w1f = (const bf16x8*)w1p;
    #pragma unroll
    for (int kt = 0; kt < 4; kt++) {
        bf16x8 af = *(const bf16x8*)&hid[wave][l15][kt*32 + lg*8];
        #pragma unroll
        for (int nt = 0; nt < 8; nt++) {
            bf16x8 bfr = w1f[(size_t)(kt*8 + nt)*64 + lane];
            acc2[nt] = __builtin_amdgcn_mfma_f32_16x16x32_bf16(af, bfr, acc2[nt], 0, 0, 0);
        }
    }
    float t[8][4];
    #pragma unroll
    for (int nt = 0; nt < 8; nt++) {
        int col = nt*16 + l15;
        float bb = b1[col];
        #pragma unroll
        for (int j = 0; j < 4; j++) {
            long long nrow = nbase + lg*4 + j;
            long long nrc  = nrow < N_NODES ? nrow : (N_NODES - 1);
            float res = XF32IN ? xf_in[nrc*128 + col] : bf2f(xb_in[nrc*128 + col]);
            t[nt][j] = acc2[nt][j] + bb + res;
        }
    }
    float xo[8][4];
    #pragma unroll
    for (int j = 0; j < 4; j++) {
        float s = 0.f;
        #pragma unroll
        for (int nt = 0; nt < 8; nt++) s += t[nt][j];
        #pragma unroll
        for (int m = 1; m < 16; m <<= 1) s += __shfl_xor(s, m);
        float mean = s * (1.0f / 128.0f);
        float s2 = 0.f;
        #pragma unroll
        for (int nt = 0; nt < 8; nt++) { float d = t[nt][j] - mean; s2 += d*d; }
        #pragma unroll
        for (int m = 1; m < 16; m <<= 1) s2 += __shfl_xor(s2, m);
        float rstd = rsqrtf(s2 * (1.0f / 128.0f) + 1e-5f);
        long long nrow = nbase + lg*4 + j;
        #pragma unroll
        for (int nt = 0; nt < 8; nt++) {
            int col = nt*16 + l15;
            float v = (t[nt][j] - mean) * rstd * lng[col] + lnb[col];
            xo[nt][j] = v;
            if (XF32OUT && nrow < N_NODES) xf_out[nrow*128 + col] = v;
        }
    }

    if (!XF32OUT || MAKEPQ) {
        // stage LN'd x (bf16) into drained hid tile
        LGKM0();   // layer1 ds_reads drained
        #pragma unroll
        for (int nt = 0; nt < 8; nt++) {
            int col = nt*16 + l15;
            #pragma unroll
            for (int j = 0; j < 4; j++)
                hid[wave][lg*4 + j][col] = f2bf(xo[nt][j]);
        }
        LGKM0();
    }

    if (!XF32OUT) {
        // wide coalesced bf16 x store: wave streams its 16 rows (4KB)
        #pragma unroll
        for (int k = 0; k < 4; k++) {
            int row = k*4 + (lane >> 4);
            long long nrow = nbase + row;
            bf16x8 vv = *(const bf16x8*)&hid[wave][row][l15*8];
            if (nrow < N_NODES)
                *(bf16x8*)&xb_out[nrow*128 + l15*8] = vv;
        }
    }

    if (MAKEPQ) {
        const bf16x8* wn = (const bf16x8*)wnext;
        // ---- P = x @ W0a' (x from hid), wide store via outt ----
        {
            f32x4 accP[8] = {};
            #pragma unroll
            for (int kt = 0; kt < 4; kt++) {
                bf16x8 af = *(const bf16x8*)&hid[wave][l15][kt*32 + lg*8];
                #pragma unroll
                for (int nt = 0; nt < 8; nt++)
                    accP[nt] = __builtin_amdgcn_mfma_f32_16x16x32_bf16(af, wn[(size_t)(kt*8 + nt)*64 + lane], accP[nt], 0, 0, 0);
            }
            LGKM0();
            #pragma unroll
            for (int nt = 0; nt < 8; nt++) {
                int col = nt*16 + l15;
                #pragma unroll
                for (int j = 0; j < 4; j++)
                    outt[wave][lg*4 + j][col] = f2bf(accP[nt][j]);
            }
            LGKM0();
            #pragma unroll
            for (int k = 0; k < 4; k++) {
                int row = k*4 + (lane >> 4);
                long long nrow = nbase + row;
                bf16x8 vv = *(const bf16x8*)&outt[wave][row][l15*8];
                if (nrow < N_NODES)
                    *(bf16x8*)&P[nrow*128 + l15*8] = vv;
            }
            LGKM0();   // outt reads done -> reusable
        }
        // ---- Q = x @ W0b' (x from hid), wide store via outt ----
        {
            f32x4 accQ[8] = {};
            #pragma unroll
            for (int kt = 0; kt < 4; kt++) {
                bf16x8 af = *(const bf16x8*)&hid[wave][l15][kt*32 + lg*8];
                #pragma unroll
                for (int nt = 0; nt < 8; nt++)
                    accQ[nt] = __builtin_amdgcn_mfma_f32_16x16x32_bf16(af, wn[(size_t)((kt+4)*8 + nt)*64 + lane], accQ[nt], 0, 0, 0);
            }
            LGKM0();
            #pragma unroll
            for (int nt = 0; nt < 8; nt++) {
                int col = nt*16 + l15;
                #pragma unroll
                for (int j = 0; j < 4; j++)
                    outt[wave][lg*4 + j][col] = f2bf(accQ[nt][j]);
            }
            LGKM0();
            #pragma unroll
            for (int k = 0; k < 4; k++) {
                int row = k*4 + (lane >> 4);
                long long nrow = nbase + row;
                bf16x8 vv = *(const bf16x8*)&outt[wave][row][l15*8];
                if (nrow < N_NODES)
                    *(bf16x8*)&Q[nrow*128 + l15*8] = vv;
            }
        }
    }
}

extern "C" void kernel_launch(void* const* d_in, const int* in_sizes, int n_in,
                              void* d_out, int out_size, void* d_ws, size_t ws_size,
                              hipStream_t stream) {
    const float* x_in   = (const float*)d_in[0];
    const int*   eidx   = (const int*)d_in[1];
    const float* ea_in0 = (const float*)d_in[2];
    const float* ew0  = (const float*)d_in[5];
    const float* eb0  = (const float*)d_in[6];
    const float* ew1  = (const float*)d_in[7];
    const float* eb1  = (const float*)d_in[8];
    const float* elng = (const float*)d_in[9];
    const float* elnb = (const float*)d_in[10];
    const float* nw0  = (const float*)d_in[11];
    const float* nb0  = (const float*)d_in[12];
    const float* nw1  = (const float*)d_in[13];
    const float* nb1  = (const float*)d_in[14];
    const float* nlng = (const float*)d_in[15];
    const float* nlnb = (const float*)d_in[16];
    const int* srcI = eidx;
    const int* tgtI = eidx + N_EDGES;

    // ---- workspace layout (bytes) ----
    char* ws = (char*)d_ws;
    size_t o = 0;
    short* ea_bf  = (short*)(ws + o); o += (size_t)N_EDGES * 128 * 2;       // 153.6 MB (permuted)
    short* Pb     = (short*)(ws + o); o += (size_t)N_NODES * 128 * 2;       // 25.6 MB
    short* Qb     = (short*)(ws + o); o += (size_t)N_NODES * 128 * 2;       // 25.6 MB
    short* xbA    = (short*)(ws + o); o += (size_t)N_NODES * 128 * 2;       // 25.6 MB
    short* xbB    = (short*)(ws + o); o += (size_t)N_NODES * 128 * 2;       // 25.6 MB
    short* wpack  = (short*)(ws + o); o += (size_t)NMP * 114688 * 2;        // 0.92 MB
    int*   deg    = (int*)(ws + o);   o += (size_t)N_NODES * 4;
    int*   offA   = (int*)(ws + o);   o += (size_t)(N_NODES + 1) * 4;
    int*   cursor = (int*)(ws + o);   o += (size_t)N_NODES * 4;
    int*   bsum   = (int*)(ws + o);   o += (size_t)NB_SCAN * 4;
    int*   bbase  = (int*)(ws + o);   o += (size_t)NB_SCAN * 4;
    int*   elist  = (int*)(ws + o);   o += (size_t)N_EDGES * 4;
    int*   psrc   = (int*)(ws + o);   o += (size_t)N_EDGES * 4;
    int*   ptgt   = (int*)(ws + o);   o += (size_t)N_EDGES * 4;
    float* xbuf   = (float*)d_out;

    // ---- one-time: weight pack + CSR + permuted index arrays ----
    pack_weights<<<(NMP * 14336 + 255) / 256, 256, 0, stream>>>(ew0, ew1, nw0, nw1, wpack);
    hipMemsetAsync(deg, 0, (size_t)N_NODES * 4, stream);
    deg_count<<<(N_EDGES + 255) / 256, 256, 0, stream>>>(tgtI, deg);
    scan_reduce<<<NB_SCAN, 256, 0, stream>>>(deg, bsum);
    scan_top<<<1, 64, 0, stream>>>(bsum, bbase, offA);
    scan_apply<<<NB_SCAN, 256, 0, stream>>>(deg, bbase, offA, cursor);
    fill_csr<<<(N_EDGES + 255) / 256, 256, 0, stream>>>(tgtI, cursor, elist);
    build_perm<<<(N_EDGES + 255) / 256, 256, 0, stream>>>(srcI, tgtI, elist, psrc, ptgt);

    const int ngrid = (N_NODES + 63) / 64;
    const int egrid = (N_EDGES + 127) / 128;
    // iter-0 P/Q from input x
    xform_kernel<<<ngrid, 256, 0, stream>>>(x_in, Pb, Qb, wpack);

    // bf16 x ping-pong: iter0 writes xbA; iter1 xbA->xbB; iter2 xbB->xbA;
    // iter3 reads xbA, writes f32 d_out.
    short* xbin[4]  = {nullptr, xbA, xbB, xbA};
    short* xbout[4] = {xbA, xbB, xbA, nullptr};

    for (int i = 0; i < NMP; i++) {
        const short* wp = wpack + (size_t)i * 114688;
        const short* wnext = wpack + (size_t)(i + 1) * 114688;   // unused when i==3
        if (i == 0) {
            edge_kernel<true><<<egrid, 512, 0, stream>>>(
                Pb, Qb, (const void*)ea_in0, ea_bf, psrc, ptgt, elist,
                wp + 0,
                eb0 + i * 128, eb1 + i * 128, elng + i * 128, elnb + i * 128);
        } else {
            edge_kernel<false><<<egrid, 512, 0, stream>>>(
                Pb, Qb, (const void*)ea_bf, ea_bf, psrc, ptgt, elist,
                wp + 0,
                eb0 + i * 128, eb1 + i * 128, elng + i * 128, elnb + i * 128);
        }
        if (i == 0) {
            node_kernel<true, false, true><<<ngrid, 256, 0, stream>>>(
                x_in, nullptr, nullptr, xbout[i], ea_bf, offA,
                wp + 65536, wp + 98304, wnext, Pb, Qb,
                nb0 + i * 128, nb1 + i * 128, nlng + i * 128, nlnb + i * 128);
        } else if (i < NMP - 1) {
            node_kernel<false, false, true><<<ngrid, 256, 0, stream>>>(
                nullptr, xbin[i], nullptr, xbout[i], ea_bf, offA,
                wp + 65536, wp + 98304, wnext, Pb, Qb,
                nb0 + i * 128, nb1 + i * 128, nlng + i * 128, nlnb + i * 128);
        } else {
            node_kernel<false, true, false><<<ngrid, 256, 0, stream>>>(
                nullptr, xbin[i], xbuf, nullptr, ea_bf, offA,
                wp + 65536, wp + 98304, wnext, Pb, Qb,
                nb0 + i * 128, nb1 + i * 128, nlng + i * 128, nlnb + i * 128);
        }
    }
}